// Round 12
// baseline (1153.146 us; speedup 1.0000x reference)
//
#include <hip/hip_runtime.h>
#include <math.h>
#include <stdint.h>

#define B_   2
#define L_   2048
#define T_   (B_ * L_)      // 4096 tokens
#define V_   32000
#define DM_  768
#define NL_  4
#define NS_  16             // d_state
#define KC_  4              // d_conv
#define ED_  1536           // d_inner
#define DTR_ 48             // dt_rank
#define DBCP_ 128           // padded dbc row stride (was 80)
#define NCH_ 64             // scan chunks (e-lane layout needs more chunks for occupancy)
#define SCH_ (L_ / NCH_)    // chunk length = 32

typedef __attribute__((ext_vector_type(8))) short short8;
typedef __attribute__((ext_vector_type(4))) float f32x4;

__device__ __forceinline__ float siluf(float x) { return x / (1.f + __expf(-x)); }

__device__ __forceinline__ unsigned short f2bf1(float f) {
    union { float f; uint32_t u; } c; c.f = f;
    uint32_t u = c.u;
    uint32_t r = (u + 0x7FFFu + ((u >> 16) & 1u)) >> 16;   // RNE
    return (unsigned short)r;
}

// ---------------------------------------------------------------------------
// Merged upfront weight conversion (one dispatch replaces 5)
// ---------------------------------------------------------------------------
#define PREP_B0 9216
#define PREP_B1 13824
#define PREP_B2 14592
#define PREP_B3 14976
#define PREP_NB 38976

__global__ __launch_bounds__(256)
void prep_kernel(const float* __restrict__ inw, unsigned short* __restrict__ inw_bf,
                 const float* __restrict__ outw, unsigned short* __restrict__ outw_bf,
                 const float* __restrict__ wx, unsigned short* __restrict__ wx_bf,
                 const float* __restrict__ wdt, unsigned short* __restrict__ wdt_bf,
                 const float* __restrict__ hw, unsigned short* __restrict__ hw_bf)
{
    const int b = blockIdx.x;
    const int tid = threadIdx.x;

    if (b < PREP_B0) {                       // in_proj plain f2bf
        int i = b * 256 + tid;               // over NL*2ED*DM/4
        float4 v = reinterpret_cast<const float4*>(inw)[i];
        ushort4 o;
        o.x = f2bf1(v.x); o.y = f2bf1(v.y); o.z = f2bf1(v.z); o.w = f2bf1(v.w);
        reinterpret_cast<ushort4*>(inw_bf)[i] = o;
    } else if (b < PREP_B1) {                // out_proj plain f2bf
        int i = (b - PREP_B0) * 256 + tid;   // over NL*DM*ED/4
        float4 v = reinterpret_cast<const float4*>(outw)[i];
        ushort4 o;
        o.x = f2bf1(v.x); o.y = f2bf1(v.y); o.z = f2bf1(v.z); o.w = f2bf1(v.w);
        reinterpret_cast<ushort4*>(outw_bf)[i] = o;
    } else if (b < PREP_B2) {                // x_proj pad
        int i = (b - PREP_B1) * 256 + tid;   // over NL*128*ED/4
        int e4 = i * 4;
        int l  = e4 / (128 * ED_);
        int r  = (e4 / ED_) % 128;
        int c  = e4 % ED_;
        ushort4 o;
        if (r < 80) {
            const float* s = wx + (size_t)l * 80 * ED_ + (size_t)r * ED_ + c;
            float4 v = *reinterpret_cast<const float4*>(s);
            o.x = f2bf1(v.x); o.y = f2bf1(v.y); o.z = f2bf1(v.z); o.w = f2bf1(v.w);
        } else {
            o.x = o.y = o.z = o.w = 0;
        }
        reinterpret_cast<ushort4*>(wx_bf)[i] = o;
    } else if (b < PREP_B3) {                // dt_proj pad
        int i = (b - PREP_B2) * 256 + tid;   // over NL*ED*64/4
        int e4 = i * 4;
        int l  = e4 / (ED_ * 64);
        int e  = (e4 / 64) % ED_;
        int k  = e4 % 64;
        ushort4 o;
        if (k < DTR_) {    // 4-groups never straddle 48
            const float* s = wdt + (size_t)l * ED_ * DTR_ + (size_t)e * DTR_ + k;
            float4 v = *reinterpret_cast<const float4*>(s);
            o.x = f2bf1(v.x); o.y = f2bf1(v.y); o.z = f2bf1(v.z); o.w = f2bf1(v.w);
        } else {
            o.x = o.y = o.z = o.w = 0;
        }
        reinterpret_cast<ushort4*>(wdt_bf)[i] = o;
    } else {                                 // head_w plain f2bf
        int i = (b - PREP_B3) * 256 + tid;   // over V*DM/4
        float4 v = reinterpret_cast<const float4*>(hw)[i];
        ushort4 o;
        o.x = f2bf1(v.x); o.y = f2bf1(v.y); o.z = f2bf1(v.z); o.w = f2bf1(v.w);
        reinterpret_cast<ushort4*>(hw_bf)[i] = o;
    }
}

// ---------------------------------------------------------------------------
// Embedding gather -> x bf16 only
// ---------------------------------------------------------------------------
__global__ __launch_bounds__(256)
void embed_kernel(const int* __restrict__ ids, const float* __restrict__ emb,
                  unsigned short* __restrict__ x_bf)
{
    int i = blockIdx.x * 256 + threadIdx.x;
    if (i >= T_ * DM_) return;
    int t = i / DM_;
    int d = i - t * DM_;
    x_bf[i] = f2bf1(emb[(size_t)ids[t] * DM_ + d]);
}

// ---------------------------------------------------------------------------
// bf16 MFMA NT GEMM (m97 structure, generalized)
// ---------------------------------------------------------------------------
template<int ACT, bool DUAL>
__global__ __launch_bounds__(256)
void gemm_bf16(const unsigned short* __restrict__ A, int lda,
               const unsigned short* __restrict__ Bw, int ldb,
               float* __restrict__ C, unsigned short* __restrict__ Cbf, int ldc,
               const float* __restrict__ bias, int nm, int K)
{
    __shared__ short As[128 * 32];
    __shared__ short Bs[128 * 32];

    const int nwg = gridDim.x;
    const int bid = blockIdx.x;
    const int q = nwg >> 3, r = nwg & 7;
    const int xcd = bid & 7, idx = bid >> 3;
    const int s = (xcd < r ? xcd * (q + 1) : r * (q + 1) + (xcd - r) * q) + idx;
    const int bm = (s % nm) * 128;
    const int bn = (s / nm) * 128;

    const int tid = threadIdx.x;
    const int l    = tid & 63;
    const int wid  = tid >> 6;
    const int wr   = wid >> 1;
    const int wc   = wid & 1;
    const int lrow = l & 15;
    const int kg   = l >> 4;

    const int sr = tid >> 2;
    const int sc = (tid & 3) * 8;
    const unsigned short* gA0 = A  + (size_t)(bm + sr) * lda + sc;
    const unsigned short* gA1 = A  + (size_t)(bm + sr + 64) * lda + sc;
    const unsigned short* gB0 = Bw + (size_t)(bn + sr) * ldb + sc;
    const unsigned short* gB1 = Bw + (size_t)(bn + sr + 64) * ldb + sc;
    short* lA0 = As + tid * 8;
    short* lA1 = As + tid * 8 + 2048;
    short* lB0 = Bs + tid * 8;
    short* lB1 = Bs + tid * 8 + 2048;

    f32x4 acc[4][4] = {};

    const int aBase = (wr * 64 + lrow) * 32 + kg * 8;
    const int bBase = (wc * 64 + lrow) * 32 + kg * 8;

    for (int k0 = 0; k0 < K; k0 += 32) {
        __builtin_amdgcn_global_load_lds((const __attribute__((address_space(1))) uint32_t*)(gA0 + k0),
                                         (__attribute__((address_space(3))) uint32_t*)lA0, 16, 0, 0);
        __builtin_amdgcn_global_load_lds((const __attribute__((address_space(1))) uint32_t*)(gA1 + k0),
                                         (__attribute__((address_space(3))) uint32_t*)lA1, 16, 0, 0);
        __builtin_amdgcn_global_load_lds((const __attribute__((address_space(1))) uint32_t*)(gB0 + k0),
                                         (__attribute__((address_space(3))) uint32_t*)lB0, 16, 0, 0);
        __builtin_amdgcn_global_load_lds((const __attribute__((address_space(1))) uint32_t*)(gB1 + k0),
                                         (__attribute__((address_space(3))) uint32_t*)lB1, 16, 0, 0);
        __syncthreads();

        short8 af[4], bf[4];
        #pragma unroll
        for (int i = 0; i < 4; ++i)
            af[i] = *reinterpret_cast<const short8*>(&As[aBase + i * 16 * 32]);
        #pragma unroll
        for (int j = 0; j < 4; ++j)
            bf[j] = *reinterpret_cast<const short8*>(&Bs[bBase + j * 16 * 32]);
        #pragma unroll
        for (int i = 0; i < 4; ++i)
            #pragma unroll
            for (int j = 0; j < 4; ++j)
                acc[i][j] = __builtin_amdgcn_mfma_f32_16x16x32_bf16(af[i], bf[j], acc[i][j], 0, 0, 0);
        __syncthreads();
    }

    const int rb = kg * 4;
    #pragma unroll
    for (int i = 0; i < 4; ++i) {
        const int row = bm + wr * 64 + i * 16 + rb;
        #pragma unroll
        for (int j = 0; j < 4; ++j) {
            const int col = bn + wc * 64 + j * 16 + lrow;
            const float b = bias ? bias[col] : 0.f;
            #pragma unroll
            for (int rr = 0; rr < 4; ++rr) {
                float v = acc[i][j][rr] + b;
                if (ACT == 1) v = fmaxf(v, 0.f) + __logf(1.f + __expf(-fabsf(v)));  // softplus
                C[(size_t)(row + rr) * ldc + col] = v;
                if (DUAL) Cbf[(size_t)(row + rr) * ldc + col] = f2bf1(v);
            }
        }
    }
}

// ---------------------------------------------------------------------------
// Split-K m97 GEMM + reduction (round-10 win: co-residency for long-K GEMMs)
// ---------------------------------------------------------------------------
__global__ __launch_bounds__(256)
void gemm_splitk_bf16(const unsigned short* __restrict__ A, int lda,
                      const unsigned short* __restrict__ Bw, int ldb,
                      float* __restrict__ P, int ldc, int nm, int S, int kc)
{
    __shared__ short As[128 * 32];
    __shared__ short Bs[128 * 32];

    const int nwg = gridDim.x;
    const int bid = blockIdx.x;
    const int q = nwg >> 3, r = nwg & 7;
    const int xcd = bid & 7, idx = bid >> 3;
    const int s = (xcd < r ? xcd * (q + 1) : r * (q + 1) + (xcd - r) * q) + idx;
    const int ntile = nwg / S;
    const int bt = s % ntile;
    const int km = s / ntile;
    const int bm = (bt % nm) * 128;
    const int bn = (bt / nm) * 128;

    const int tid = threadIdx.x;
    const int l    = tid & 63;
    const int wid  = tid >> 6;
    const int wr   = wid >> 1;
    const int wc   = wid & 1;
    const int lrow = l & 15;
    const int kg   = l >> 4;

    const int kbase = km * kc;
    const int sr = tid >> 2;
    const int sc = (tid & 3) * 8;
    const unsigned short* gA0 = A  + (size_t)(bm + sr) * lda + sc + kbase;
    const unsigned short* gA1 = A  + (size_t)(bm + sr + 64) * lda + sc + kbase;
    const unsigned short* gB0 = Bw + (size_t)(bn + sr) * ldb + sc + kbase;
    const unsigned short* gB1 = Bw + (size_t)(bn + sr + 64) * ldb + sc + kbase;
    short* lA0 = As + tid * 8;
    short* lA1 = As + tid * 8 + 2048;
    short* lB0 = Bs + tid * 8;
    short* lB1 = Bs + tid * 8 + 2048;

    f32x4 acc[4][4] = {};

    const int aBase = (wr * 64 + lrow) * 32 + kg * 8;
    const int bBase = (wc * 64 + lrow) * 32 + kg * 8;

    for (int k0 = 0; k0 < kc; k0 += 32) {
        __builtin_amdgcn_global_load_lds((const __attribute__((address_space(1))) uint32_t*)(gA0 + k0),
                                         (__attribute__((address_space(3))) uint32_t*)lA0, 16, 0, 0);
        __builtin_amdgcn_global_load_lds((const __attribute__((address_space(1))) uint32_t*)(gA1 + k0),
                                         (__attribute__((address_space(3))) uint32_t*)lA1, 16, 0, 0);
        __builtin_amdgcn_global_load_lds((const __attribute__((address_space(1))) uint32_t*)(gB0 + k0),
                                         (__attribute__((address_space(3))) uint32_t*)lB0, 16, 0, 0);
        __builtin_amdgcn_global_load_lds((const __attribute__((address_space(1))) uint32_t*)(gB1 + k0),
                                         (__attribute__((address_space(3))) uint32_t*)lB1, 16, 0, 0);
        __syncthreads();

        short8 af[4], bf[4];
        #pragma unroll
        for (int i = 0; i < 4; ++i)
            af[i] = *reinterpret_cast<const short8*>(&As[aBase + i * 16 * 32]);
        #pragma unroll
        for (int j = 0; j < 4; ++j)
            bf[j] = *reinterpret_cast<const short8*>(&Bs[bBase + j * 16 * 32]);
        #pragma unroll
        for (int i = 0; i < 4; ++i)
            #pragma unroll
            for (int j = 0; j < 4; ++j)
                acc[i][j] = __builtin_amdgcn_mfma_f32_16x16x32_bf16(af[i], bf[j], acc[i][j], 0, 0, 0);
        __syncthreads();
    }

    float* Pk = P + (size_t)km * T_ * ldc;
    const int rb = kg * 4;
    #pragma unroll
    for (int i = 0; i < 4; ++i) {
        const int row = bm + wr * 64 + i * 16 + rb;
        #pragma unroll
        for (int j = 0; j < 4; ++j) {
            const int col = bn + wc * 64 + j * 16 + lrow;
            #pragma unroll
            for (int rr = 0; rr < 4; ++rr)
                Pk[(size_t)(row + rr) * ldc + col] = acc[i][j][rr];
        }
    }
}

__global__ __launch_bounds__(256)
void reduce_splitk(const float* __restrict__ P, float* __restrict__ C,
                   unsigned short* __restrict__ Cbf, int n4, int S)
{
    int i = blockIdx.x * 256 + threadIdx.x;
    if (i >= n4) return;
    const float4* P4 = reinterpret_cast<const float4*>(P);
    float4 a = P4[i];
    for (int s = 1; s < S; ++s) {
        float4 b = P4[i + (size_t)s * n4];
        a.x += b.x; a.y += b.y; a.z += b.z; a.w += b.w;
    }
    reinterpret_cast<float4*>(C)[i] = a;
    ushort4 o;
    o.x = f2bf1(a.x); o.y = f2bf1(a.y); o.z = f2bf1(a.z); o.w = f2bf1(a.w);
    reinterpret_cast<ushort4*>(Cbf)[i] = o;
}

// ---------------------------------------------------------------------------
// 256x256 8-wave deep-pipelined bf16 GEMM (head + xz projection).
// Round-12: compute split into 4 phases of 16 MFMA per K-tile — phase =
// (kk half, mh half of the wave's 128 rows). Each phase: {4-8 ds_read_b128;
// s_barrier; setprio(1); 16 MFMA; setprio(0); s_barrier}. Small MFMA
// clusters + barrier pacing give the CU scheduler wave role-diversity
// (one wave's ds_reads overlap another's MFMA) — the T3/T5 prerequisite
// the monolithic 64-MFMA region denied. Reads stay at the 24/tile minimum
// (Bf held across the two mh phases of each kk). Staging unchanged:
// all-at-tile-start, counted vmcnt(8), never 0 in the main loop.
// ---------------------------------------------------------------------------
#define GBAR() do { asm volatile("" ::: "memory"); \
                    __builtin_amdgcn_s_barrier();  \
                    asm volatile("" ::: "memory"); } while (0)

__global__ __launch_bounds__(512, 2)
void gemm256_bf16(const unsigned short* __restrict__ A, int lda,
                  const unsigned short* __restrict__ Bw, int ldb,
                  float* __restrict__ C, int ldc,
                  const float* __restrict__ bias, int nm, int K)
{
    __shared__ __align__(16) char lds[131072];

    const int nwg = gridDim.x;
    const int bid = blockIdx.x;
    const int q = nwg >> 3, r = nwg & 7;
    const int xcd = bid & 7, idx = bid >> 3;
    const int s = (xcd < r ? xcd * (q + 1) : r * (q + 1) + (xcd - r) * q) + idx;
    const int bm = (s % nm) * 256;
    const int bn = (s / nm) * 256;

    const int tid = threadIdx.x;
    const int l   = tid & 63;
    const int wid = tid >> 6;      // 0..7
    const int wm  = wid >> 2;      // 0..1 (M half)
    const int wn  = wid & 3;       // 0..3 (N quarter)

    const int scb = (tid & 7) * 16;                 // linear LDS byte col
    const int ssw = ((tid >> 3) & 7) << 4;          // row-derived swizzle
    const int scol = (scb ^ ssw) >> 1;              // global col in shorts
    const unsigned short* gA = A  + (size_t)(bm + (tid >> 3)) * lda + scol;
    const unsigned short* gB = Bw + (size_t)(bn + (tid >> 3)) * ldb + scol;
    char* const ldsA = lds + tid * 16;              // + sel*32768 + rr*8192
    char* const ldsB = lds + 65536 + tid * 16;

#define STAGE256(kt, sel)                                                          \
    do {                                                                           \
        const unsigned short* _a = gA + (size_t)(kt) * 64;                         \
        const unsigned short* _b = gB + (size_t)(kt) * 64;                         \
        char* _la = ldsA + (sel) * 32768;                                          \
        char* _lb = ldsB + (sel) * 32768;                                          \
        _Pragma("unroll")                                                          \
        for (int _r = 0; _r < 4; ++_r) {                                           \
            __builtin_amdgcn_global_load_lds(                                      \
                (const __attribute__((address_space(1))) uint32_t*)(_a + (size_t)_r * 64 * lda), \
                (__attribute__((address_space(3))) uint32_t*)(_la + _r * 8192), 16, 0, 0);       \
            __builtin_amdgcn_global_load_lds(                                      \
                (const __attribute__((address_space(1))) uint32_t*)(_b + (size_t)_r * 64 * ldb), \
                (__attribute__((address_space(3))) uint32_t*)(_lb + _r * 8192), 16, 0, 0);       \
        }                                                                          \
    } while (0)

    const int lrow = l & 15;
    const int hi   = (l >> 4) * 16;                 // k-group byte offset 0..48
    const int swl  = (l & 7) << 4;                  // row-derived swizzle (row&7==l&7)
    const int x0   = hi ^ swl;                      // kk=0 swizzled k-byte
    const int x1   = (64 + hi) ^ swl;               // kk=1 swizzled k-byte
    const int aRowB = (wm * 128 + lrow) * 128;      // byte offset of frag row 0
    const int bRowB = (wn * 64 + lrow) * 128;

    f32x4 acc[8][4] = {};

    const int NT = K >> 6;
    STAGE256(0, 0);

    for (int t = 0; t < NT; ++t) {
        const int sel = t & 1;
        if (t + 1 < NT) {
            STAGE256(t + 1, sel ^ 1);
            asm volatile("s_waitcnt vmcnt(8)" ::: "memory");   // tile t landed; t+1 in flight
        } else {
            asm volatile("s_waitcnt vmcnt(0)" ::: "memory");   // tail drain
        }
        GBAR();

        const char* bufA = lds + sel * 32768;
        const char* bufB = lds + 65536 + sel * 32768;

        short8 Af[4], Bf[4];
        #pragma unroll
        for (int kk = 0; kk < 2; ++kk) {
            const int xo = kk ? x1 : x0;

            // phase (kk, mh=0): read A rows 0-63 of wave-half + all 4 B frags
            #pragma unroll
            for (int mi = 0; mi < 4; ++mi)
                Af[mi] = *reinterpret_cast<const short8*>(bufA + aRowB + mi * 16 * 128 + xo);
            #pragma unroll
            for (int ni = 0; ni < 4; ++ni)
                Bf[ni] = *reinterpret_cast<const short8*>(bufB + bRowB + ni * 16 * 128 + xo);
            GBAR();
            __builtin_amdgcn_s_setprio(1);
            #pragma unroll
            for (int mi = 0; mi < 4; ++mi)
                #pragma unroll
                for (int ni = 0; ni < 4; ++ni)
                    acc[mi][ni] = __builtin_amdgcn_mfma_f32_16x16x32_bf16(
                        Af[mi], Bf[ni], acc[mi][ni], 0, 0, 0);
            __builtin_amdgcn_s_setprio(0);
            GBAR();

            // phase (kk, mh=1): read A rows 64-127 of wave-half (B held)
            #pragma unroll
            for (int mi = 0; mi < 4; ++mi)
                Af[mi] = *reinterpret_cast<const short8*>(bufA + aRowB + (64 + mi * 16) * 128 + xo);
            GBAR();
            __builtin_amdgcn_s_setprio(1);
            #pragma unroll
            for (int mi = 0; mi < 4; ++mi)
                #pragma unroll
                for (int ni = 0; ni < 4; ++ni)
                    acc[4 + mi][ni] = __builtin_amdgcn_mfma_f32_16x16x32_bf16(
                        Af[mi], Bf[ni], acc[4 + mi][ni], 0, 0, 0);
            __builtin_amdgcn_s_setprio(0);
            GBAR();
        }
    }

    const int rg = (l >> 4) * 4;
    #pragma unroll
    for (int mf = 0; mf < 8; ++mf) {
        const int row = bm + wm * 128 + mf * 16 + rg;
        #pragma unroll
        for (int nf = 0; nf < 4; ++nf) {
            const int col = bn + wn * 64 + nf * 16 + lrow;
            const float bb = bias ? bias[col] : 0.f;
            #pragma unroll
            for (int rr2 = 0; rr2 < 4; ++rr2)
                C[(size_t)(row + rr2) * ldc + col] = acc[mf][nf][rr2] + bb;
        }
    }
#undef STAGE256
}

// ---------------------------------------------------------------------------
// Depthwise causal conv (K=4) + bias + SiLU -> u fp32 + u bf16
// ---------------------------------------------------------------------------
__global__ __launch_bounds__(256)
void conv_silu_kernel(const float* __restrict__ xz, const float* __restrict__ cw,
                      const float* __restrict__ cb, float* __restrict__ u,
                      unsigned short* __restrict__ u_bf)
{
    int idx = blockIdx.x * 256 + threadIdx.x;
    if (idx >= T_ * ED_) return;
    int e = idx % ED_;
    int t = idx / ED_;
    int l = t % L_;

    float acc = cb[e];
    #pragma unroll
    for (int k = 0; k < KC_; ++k) {
        int ll = l - (KC_ - 1) + k;
        if (ll >= 0)
            acc += cw[e * KC_ + k] * xz[(size_t)(t - (KC_ - 1) + k) * (2 * ED_) + e];
    }
    float v = siluf(acc);
    u[idx] = v;
    u_bf[idx] = f2bf1(v);
}

// ---------------------------------------------------------------------------
// Chunked selective scan, e-lane layout (round-11 win: coalesced loads,
// states in registers, no shuffles)
// ---------------------------------------------------------------------------
__global__ __launch_bounds__(256)
void scanA_kernel(const float* __restrict__ delta,
                  const float* __restrict__ dbc,
                  const float* __restrict__ u,
                  const float* __restrict__ A_log,
                  float* __restrict__ hend,
                  float* __restrict__ Pcum)
{
    const int b = blockIdx.z;
    const int c = blockIdx.y;
    const int e = blockIdx.x * 256 + threadIdx.x;

    float Aen[16], h[16], P[16];
    #pragma unroll
    for (int n = 0; n < NS_; ++n) {
        Aen[n] = -__expf(A_log[e * NS_ + n]);
        h[n] = 0.f; P[n] = 1.f;
    }

    const int t0 = b * L_ + c * SCH_;
    #pragma unroll 2
    for (int l = 0; l < SCH_; ++l) {
        const size_t t = (size_t)(t0 + l);
        const float d  = delta[t * ED_ + e];
        const float uu = u[t * ED_ + e];
        const float du = d * uu;
        const float4* Bv = reinterpret_cast<const float4*>(&dbc[t * DBCP_ + DTR_]);
        #pragma unroll
        for (int g = 0; g < 4; ++g) {
            const float4 Bg = Bv[g];
            const float Bx[4] = {Bg.x, Bg.y, Bg.z, Bg.w};
            #pragma unroll
            for (int j = 0; j < 4; ++j) {
                const int n = g * 4 + j;
                const float a = __expf(d * Aen[n]);
                h[n] = fmaf(a, h[n], du * Bx[j]);
                P[n] *= a;
            }
        }
    }
    const size_t base = ((size_t)(b * NCH_ + c) * 16) * ED_ + e;
    #pragma unroll
    for (int n = 0; n < NS_; ++n) {
        hend[base + (size_t)n * ED_] = h[n];
        Pcum[base + (size_t)n * ED_] = P[n];
    }
}

// carry pass: thread = (b, n, e); loops chunks; all loads/stores e-coalesced
__global__ __launch_bounds__(256)
void scanB2_kernel(const float* __restrict__ hend,
                   const float* __restrict__ Pcum,
                   float* __restrict__ carry)
{
    const int i = blockIdx.x * 256 + threadIdx.x;   // over B*16*ED
    const int e = i % ED_;
    const int n = (i / ED_) % 16;
    const int b = i / (16 * ED_);
    float cr = 0.f;
    #pragma unroll 4
    for (int c = 0; c < NCH_; ++c) {
        const size_t idx = (((size_t)(b * NCH_ + c) * 16) + n) * ED_ + e;
        carry[idx] = cr;
        cr = fmaf(Pcum[idx], cr, hend[idx]);
    }
}

__global__ __launch_bounds__(256)
void scanC_kernel(const float* __restrict__ delta,
                  const float* __restrict__ dbc,
                  const float* __restrict__ u,
                  const float* __restrict__ xz,
                  const float* __restrict__ A_log,
                  const float* __restrict__ Dp,
                  const float* __restrict__ carry,
                  unsigned short* __restrict__ y_bf)
{
    const int b = blockIdx.z;
    const int c = blockIdx.y;
    const int e = blockIdx.x * 256 + threadIdx.x;

    const float De = Dp[e];
    float Aen[16], h[16];
    const size_t cbase = ((size_t)(b * NCH_ + c) * 16) * ED_ + e;
    #pragma unroll
    for (int n = 0; n < NS_; ++n) {
        Aen[n] = -__expf(A_log[e * NS_ + n]);
        h[n] = carry[cbase + (size_t)n * ED_];
    }

    const int t0 = b * L_ + c * SCH_;
    #pragma unroll 2
    for (int l = 0; l < SCH_; ++l) {
        const size_t t = (size_t)(t0 + l);
        const float d  = delta[t * ED_ + e];
        const float uu = u[t * ED_ + e];
        const float du = d * uu;
        const float4* Bv = reinterpret_cast<const float4*>(&dbc[t * DBCP_ + DTR_]);
        const float4* Cv = reinterpret_cast<const float4*>(&dbc[t * DBCP_ + DTR_ + NS_]);
        float p = 0.f;
        #pragma unroll
        for (int g = 0; g < 4; ++g) {
            const float4 Bg = Bv[g];
            const float4 Cg = Cv[g];
            const float Bx[4] = {Bg.x, Bg.y, Bg.z, Bg.w};
            const float Cx[4] = {Cg.x, Cg.y, Cg.z, Cg.w};
            #pragma unroll
            for (int j = 0; j < 4; ++j) {
                const int n = g * 4 + j;
                const float a = __expf(d * Aen[n]);
                h[n] = fmaf(a, h[n], du * Bx[j]);
                p = fmaf(h[n], Cx[j], p);
            }
        }
        const float ys = p + uu * De;
        const float rr = xz[t * (2 * ED_) + ED_ + e];
        y_bf[t * ED_ + e] = f2bf1(ys * siluf(rr));
    }
}

// ---------------------------------------------------------------------------
// LayerNorm over DM, in place; also emits bf16
// ---------------------------------------------------------------------------
__global__ __launch_bounds__(256)
void ln_kernel(float* __restrict__ x, const float* __restrict__ g,
               const float* __restrict__ bta, unsigned short* __restrict__ x_bf)
{
    const int t = blockIdx.x;
    float* xr = x + (size_t)t * DM_;
    unsigned short* xb = x_bf + (size_t)t * DM_;
    const int tid = threadIdx.x;

    float v0 = xr[tid], v1 = xr[tid + 256], v2 = xr[tid + 512];
    float s  = v0 + v1 + v2;
    float sq = v0 * v0 + v1 * v1 + v2 * v2;

    __shared__ float s1[256], s2[256];
    s1[tid] = s; s2[tid] = sq;
    __syncthreads();
    for (int off = 128; off > 0; off >>= 1) {
        if (tid < off) { s1[tid] += s1[tid + off]; s2[tid] += s2[tid + off]; }
        __syncthreads();
    }
    const float mu  = s1[0] * (1.f / DM_);
    const float var = s2[0] * (1.f / DM_) - mu * mu;
    const float rs  = rsqrtf(var + 1e-5f);

    float o0 = (v0 - mu) * rs * g[tid]       + bta[tid];
    float o1 = (v1 - mu) * rs * g[tid + 256] + bta[tid + 256];
    float o2 = (v2 - mu) * rs * g[tid + 512] + bta[tid + 512];
    xr[tid] = o0;       xb[tid] = f2bf1(o0);
    xr[tid + 256] = o1; xb[tid + 256] = f2bf1(o1);
    xr[tid + 512] = o2; xb[tid + 512] = f2bf1(o2);
}

// ---------------------------------------------------------------------------
extern "C" void kernel_launch(void* const* d_in, const int* in_sizes, int n_in,
                              void* d_out, int out_size, void* d_ws, size_t ws_size,
                              hipStream_t stream)
{
    const int*   ids       = (const int*)  d_in[0];
    const float* emb       = (const float*)d_in[1];
    const float* in_proj_w = (const float*)d_in[2];
    const float* conv_w    = (const float*)d_in[3];
    const float* conv_b    = (const float*)d_in[4];
    const float* x_proj_w  = (const float*)d_in[5];
    const float* dt_proj_w = (const float*)d_in[6];
    const float* dt_proj_b = (const float*)d_in[7];
    const float* A_log     = (const float*)d_in[8];
    const float* Dp        = (const float*)d_in[9];
    const float* out_proj_w= (const float*)d_in[10];
    const float* ln_g      = (const float*)d_in[11];
    const float* ln_b      = (const float*)d_in[12];
    const float* head_w    = (const float*)d_in[13];
    const float* head_b    = (const float*)d_in[14];
    float* out = (float*)d_out;

    // fp32 workspace
    float* ws    = (float*)d_ws;
    float* x     = ws;                              // T*DM
    float* xz    = x     + (size_t)T_ * DM_;        // T*2ED
    float* u     = xz    + (size_t)T_ * 2 * ED_;    // T*ED
    float* dbc   = u     + (size_t)T_ * ED_;        // T*128 (padded)
    float* delta = dbc   + (size_t)T_ * DBCP_;      // T*ED
    float* hend  = delta + (size_t)T_ * ED_;        // B*NCH*16*ED
    float* Pcum  = hend  + (size_t)B_ * NCH_ * 16 * ED_;
    float* carry = Pcum  + (size_t)B_ * NCH_ * 16 * ED_;
    float* part  = carry + (size_t)B_ * NCH_ * 16 * ED_;  // 4*T*DM floats
    // bf16 workspace
    unsigned short* bf = (unsigned short*)(part + (size_t)4 * T_ * DM_);
    unsigned short* x_bf    = bf;                                 // T*DM
    unsigned short* u_bf    = x_bf    + (size_t)T_ * DM_;         // T*ED
    unsigned short* y_bf    = u_bf    + (size_t)T_ * ED_;         // T*ED
    unsigned short* dbc_bf  = y_bf    + (size_t)T_ * ED_;         // T*128
    unsigned short* inw_bf  = dbc_bf  + (size_t)T_ * DBCP_;       // NL*2ED*DM
    unsigned short* outw_bf = inw_bf  + (size_t)NL_ * 2 * ED_ * DM_;  // NL*DM*ED
    unsigned short* wx_bf   = outw_bf + (size_t)NL_ * DM_ * ED_;      // NL*128*ED
    unsigned short* wdt_bf  = wx_bf   + (size_t)NL_ * 128 * ED_;      // NL*ED*64
    unsigned short* hw_bf   = wdt_bf  + (size_t)NL_ * ED_ * 64;       // V*DM

    // ---- upfront: embedding + ALL weight conversions in one dispatch
    embed_kernel<<<(T_ * DM_ + 255) / 256, 256, 0, stream>>>(ids, emb, x_bf);
    prep_kernel<<<PREP_NB, 256, 0, stream>>>(
        in_proj_w, inw_bf, out_proj_w, outw_bf, x_proj_w, wx_bf,
        dt_proj_w, wdt_bf, head_w, hw_bf);

    for (int i = 0; i < NL_; ++i) {
        const unsigned short* w_in  = inw_bf  + (size_t)i * 2 * ED_ * DM_;
        const float*          cw    = conv_w  + (size_t)i * ED_ * KC_;
        const float*          cb    = conv_b  + (size_t)i * ED_;
        const unsigned short* w_x   = wx_bf   + (size_t)i * 128 * ED_;
        const unsigned short* w_dt  = wdt_bf  + (size_t)i * ED_ * 64;
        const float*          b_dt  = dt_proj_b + (size_t)i * ED_;
        const float*          al    = A_log   + (size_t)i * ED_ * NS_;
        const float*          dpar  = Dp      + (size_t)i * ED_;
        const unsigned short* w_out = outw_bf + (size_t)i * DM_ * ED_;

        // xz = x @ w_in^T  (4096 x 3072, K=768) — 256² deep-pipelined structure
        gemm256_bf16<<<(T_/256) * (2*ED_/256), 512, 0, stream>>>(
            x_bf, DM_, w_in, DM_, xz, 2 * ED_, nullptr, T_/256, DM_);

        // u = silu(depthwise causal conv + cb)  (+ bf16)
        conv_silu_kernel<<<(T_ * ED_ + 255) / 256, 256, 0, stream>>>(xz, cw, cb, u, u_bf);

        // dbc = u @ w_x_pad^T  (4096 x 128, K=1536) — split-K S=8 (32->256 blocks)
        gemm_splitk_bf16<<<(T_/128) * 1 * 8, 256, 0, stream>>>(
            u_bf, ED_, w_x, ED_, part, DBCP_, T_/128, 8, ED_/8);
        reduce_splitk<<<(T_ * DBCP_ / 4 + 255) / 256, 256, 0, stream>>>(
            part, dbc, dbc_bf, T_ * DBCP_ / 4, 8);

        // delta = softplus(dbc[:, :64] @ w_dt_pad^T + b_dt)  (4096 x 1536, K=64)
        gemm_bf16<1, false><<<(T_/128) * (ED_/128), 256, 0, stream>>>(
            dbc_bf, DBCP_, w_dt, 64, delta, nullptr, ED_, b_dt, T_/128, 64);

        // chunked selective scan + gating -> y_bf (e-lane layout, 3 passes)
        scanA_kernel<<<dim3(ED_ / 256, NCH_, B_), 256, 0, stream>>>(
            delta, dbc, u, al, hend, Pcum);
        scanB2_kernel<<<(B_ * 16 * ED_) / 256, 256, 0, stream>>>(hend, Pcum, carry);
        scanC_kernel<<<dim3(ED_ / 256, NCH_, B_), 256, 0, stream>>>(
            delta, dbc, u, xz, al, dpar, carry, y_bf);

        // x = y @ w_out^T  (4096 x 768, K=1536) — split-K S=4 (192->768 blocks)
        gemm_splitk_bf16<<<(T_/128) * (DM_/128) * 4, 256, 0, stream>>>(
            y_bf, ED_, w_out, ED_, part, DM_, T_/128, 4, ED_/4);
        reduce_splitk<<<(T_ * DM_ / 4 + 255) / 256, 256, 0, stream>>>(
            part, x, x_bf, T_ * DM_ / 4, 4);
    }

    // LayerNorm (fp32 in place + bf16), then head with the 256² deep-pipelined GEMM
    ln_kernel<<<T_, 256, 0, stream>>>(x, ln_g, ln_b, x_bf);
    gemm256_bf16<<<(T_/256) * (V_/256), 512, 0, stream>>>(
        x_bf, DM_, hw_bf, DM_, out, V_, head_b, T_/256, DM_);
}

// Round 13
// 1118.615 us; speedup vs baseline: 1.0309x; 1.0309x over previous
//
#include <hip/hip_runtime.h>
#include <math.h>
#include <stdint.h>

#define B_   2
#define L_   2048
#define T_   (B_ * L_)      // 4096 tokens
#define V_   32000
#define DM_  768
#define NL_  4
#define NS_  16             // d_state
#define KC_  4              // d_conv
#define ED_  1536           // d_inner
#define DTR_ 48             // dt_rank
#define DBCP_ 128           // padded dbc row stride (was 80)
#define NCH_ 64             // scan chunks (e-lane layout needs more chunks for occupancy)
#define SCH_ (L_ / NCH_)    // chunk length = 32

typedef __attribute__((ext_vector_type(8))) short short8;
typedef __attribute__((ext_vector_type(4))) float f32x4;

__device__ __forceinline__ float siluf(float x) { return x / (1.f + __expf(-x)); }

__device__ __forceinline__ unsigned short f2bf1(float f) {
    union { float f; uint32_t u; } c; c.f = f;
    uint32_t u = c.u;
    uint32_t r = (u + 0x7FFFu + ((u >> 16) & 1u)) >> 16;   // RNE
    return (unsigned short)r;
}

// ---------------------------------------------------------------------------
// Merged upfront weight conversion (one dispatch replaces 5)
// ---------------------------------------------------------------------------
#define PREP_B0 9216
#define PREP_B1 13824
#define PREP_B2 14592
#define PREP_B3 14976
#define PREP_NB 38976

__global__ __launch_bounds__(256)
void prep_kernel(const float* __restrict__ inw, unsigned short* __restrict__ inw_bf,
                 const float* __restrict__ outw, unsigned short* __restrict__ outw_bf,
                 const float* __restrict__ wx, unsigned short* __restrict__ wx_bf,
                 const float* __restrict__ wdt, unsigned short* __restrict__ wdt_bf,
                 const float* __restrict__ hw, unsigned short* __restrict__ hw_bf)
{
    const int b = blockIdx.x;
    const int tid = threadIdx.x;

    if (b < PREP_B0) {                       // in_proj plain f2bf
        int i = b * 256 + tid;               // over NL*2ED*DM/4
        float4 v = reinterpret_cast<const float4*>(inw)[i];
        ushort4 o;
        o.x = f2bf1(v.x); o.y = f2bf1(v.y); o.z = f2bf1(v.z); o.w = f2bf1(v.w);
        reinterpret_cast<ushort4*>(inw_bf)[i] = o;
    } else if (b < PREP_B1) {                // out_proj plain f2bf
        int i = (b - PREP_B0) * 256 + tid;   // over NL*DM*ED/4
        float4 v = reinterpret_cast<const float4*>(outw)[i];
        ushort4 o;
        o.x = f2bf1(v.x); o.y = f2bf1(v.y); o.z = f2bf1(v.z); o.w = f2bf1(v.w);
        reinterpret_cast<ushort4*>(outw_bf)[i] = o;
    } else if (b < PREP_B2) {                // x_proj pad
        int i = (b - PREP_B1) * 256 + tid;   // over NL*128*ED/4
        int e4 = i * 4;
        int l  = e4 / (128 * ED_);
        int r  = (e4 / ED_) % 128;
        int c  = e4 % ED_;
        ushort4 o;
        if (r < 80) {
            const float* s = wx + (size_t)l * 80 * ED_ + (size_t)r * ED_ + c;
            float4 v = *reinterpret_cast<const float4*>(s);
            o.x = f2bf1(v.x); o.y = f2bf1(v.y); o.z = f2bf1(v.z); o.w = f2bf1(v.w);
        } else {
            o.x = o.y = o.z = o.w = 0;
        }
        reinterpret_cast<ushort4*>(wx_bf)[i] = o;
    } else if (b < PREP_B3) {                // dt_proj pad
        int i = (b - PREP_B2) * 256 + tid;   // over NL*ED*64/4
        int e4 = i * 4;
        int l  = e4 / (ED_ * 64);
        int e  = (e4 / 64) % ED_;
        int k  = e4 % 64;
        ushort4 o;
        if (k < DTR_) {    // 4-groups never straddle 48
            const float* s = wdt + (size_t)l * ED_ * DTR_ + (size_t)e * DTR_ + k;
            float4 v = *reinterpret_cast<const float4*>(s);
            o.x = f2bf1(v.x); o.y = f2bf1(v.y); o.z = f2bf1(v.z); o.w = f2bf1(v.w);
        } else {
            o.x = o.y = o.z = o.w = 0;
        }
        reinterpret_cast<ushort4*>(wdt_bf)[i] = o;
    } else {                                 // head_w plain f2bf
        int i = (b - PREP_B3) * 256 + tid;   // over V*DM/4
        float4 v = reinterpret_cast<const float4*>(hw)[i];
        ushort4 o;
        o.x = f2bf1(v.x); o.y = f2bf1(v.y); o.z = f2bf1(v.z); o.w = f2bf1(v.w);
        reinterpret_cast<ushort4*>(hw_bf)[i] = o;
    }
}

// ---------------------------------------------------------------------------
// Embedding gather -> x bf16 only
// ---------------------------------------------------------------------------
__global__ __launch_bounds__(256)
void embed_kernel(const int* __restrict__ ids, const float* __restrict__ emb,
                  unsigned short* __restrict__ x_bf)
{
    int i = blockIdx.x * 256 + threadIdx.x;
    if (i >= T_ * DM_) return;
    int t = i / DM_;
    int d = i - t * DM_;
    x_bf[i] = f2bf1(emb[(size_t)ids[t] * DM_ + d]);
}

// ---------------------------------------------------------------------------
// bf16 MFMA NT GEMM (m97 structure, generalized)
// ---------------------------------------------------------------------------
template<int ACT, bool DUAL>
__global__ __launch_bounds__(256)
void gemm_bf16(const unsigned short* __restrict__ A, int lda,
               const unsigned short* __restrict__ Bw, int ldb,
               float* __restrict__ C, unsigned short* __restrict__ Cbf, int ldc,
               const float* __restrict__ bias, int nm, int K)
{
    __shared__ short As[128 * 32];
    __shared__ short Bs[128 * 32];

    const int nwg = gridDim.x;
    const int bid = blockIdx.x;
    const int q = nwg >> 3, r = nwg & 7;
    const int xcd = bid & 7, idx = bid >> 3;
    const int s = (xcd < r ? xcd * (q + 1) : r * (q + 1) + (xcd - r) * q) + idx;
    const int bm = (s % nm) * 128;
    const int bn = (s / nm) * 128;

    const int tid = threadIdx.x;
    const int l    = tid & 63;
    const int wid  = tid >> 6;
    const int wr   = wid >> 1;
    const int wc   = wid & 1;
    const int lrow = l & 15;
    const int kg   = l >> 4;

    const int sr = tid >> 2;
    const int sc = (tid & 3) * 8;
    const unsigned short* gA0 = A  + (size_t)(bm + sr) * lda + sc;
    const unsigned short* gA1 = A  + (size_t)(bm + sr + 64) * lda + sc;
    const unsigned short* gB0 = Bw + (size_t)(bn + sr) * ldb + sc;
    const unsigned short* gB1 = Bw + (size_t)(bn + sr + 64) * ldb + sc;
    short* lA0 = As + tid * 8;
    short* lA1 = As + tid * 8 + 2048;
    short* lB0 = Bs + tid * 8;
    short* lB1 = Bs + tid * 8 + 2048;

    f32x4 acc[4][4] = {};

    const int aBase = (wr * 64 + lrow) * 32 + kg * 8;
    const int bBase = (wc * 64 + lrow) * 32 + kg * 8;

    for (int k0 = 0; k0 < K; k0 += 32) {
        __builtin_amdgcn_global_load_lds((const __attribute__((address_space(1))) uint32_t*)(gA0 + k0),
                                         (__attribute__((address_space(3))) uint32_t*)lA0, 16, 0, 0);
        __builtin_amdgcn_global_load_lds((const __attribute__((address_space(1))) uint32_t*)(gA1 + k0),
                                         (__attribute__((address_space(3))) uint32_t*)lA1, 16, 0, 0);
        __builtin_amdgcn_global_load_lds((const __attribute__((address_space(1))) uint32_t*)(gB0 + k0),
                                         (__attribute__((address_space(3))) uint32_t*)lB0, 16, 0, 0);
        __builtin_amdgcn_global_load_lds((const __attribute__((address_space(1))) uint32_t*)(gB1 + k0),
                                         (__attribute__((address_space(3))) uint32_t*)lB1, 16, 0, 0);
        __syncthreads();

        short8 af[4], bf[4];
        #pragma unroll
        for (int i = 0; i < 4; ++i)
            af[i] = *reinterpret_cast<const short8*>(&As[aBase + i * 16 * 32]);
        #pragma unroll
        for (int j = 0; j < 4; ++j)
            bf[j] = *reinterpret_cast<const short8*>(&Bs[bBase + j * 16 * 32]);
        #pragma unroll
        for (int i = 0; i < 4; ++i)
            #pragma unroll
            for (int j = 0; j < 4; ++j)
                acc[i][j] = __builtin_amdgcn_mfma_f32_16x16x32_bf16(af[i], bf[j], acc[i][j], 0, 0, 0);
        __syncthreads();
    }

    const int rb = kg * 4;
    #pragma unroll
    for (int i = 0; i < 4; ++i) {
        const int row = bm + wr * 64 + i * 16 + rb;
        #pragma unroll
        for (int j = 0; j < 4; ++j) {
            const int col = bn + wc * 64 + j * 16 + lrow;
            const float b = bias ? bias[col] : 0.f;
            #pragma unroll
            for (int rr = 0; rr < 4; ++rr) {
                float v = acc[i][j][rr] + b;
                if (ACT == 1) v = fmaxf(v, 0.f) + __logf(1.f + __expf(-fabsf(v)));  // softplus
                C[(size_t)(row + rr) * ldc + col] = v;
                if (DUAL) Cbf[(size_t)(row + rr) * ldc + col] = f2bf1(v);
            }
        }
    }
}

// ---------------------------------------------------------------------------
// Split-K m97 GEMM + reduction (round-10 win: co-residency for long-K GEMMs)
// ---------------------------------------------------------------------------
__global__ __launch_bounds__(256)
void gemm_splitk_bf16(const unsigned short* __restrict__ A, int lda,
                      const unsigned short* __restrict__ Bw, int ldb,
                      float* __restrict__ P, int ldc, int nm, int S, int kc)
{
    __shared__ short As[128 * 32];
    __shared__ short Bs[128 * 32];

    const int nwg = gridDim.x;
    const int bid = blockIdx.x;
    const int q = nwg >> 3, r = nwg & 7;
    const int xcd = bid & 7, idx = bid >> 3;
    const int s = (xcd < r ? xcd * (q + 1) : r * (q + 1) + (xcd - r) * q) + idx;
    const int ntile = nwg / S;
    const int bt = s % ntile;
    const int km = s / ntile;
    const int bm = (bt % nm) * 128;
    const int bn = (bt / nm) * 128;

    const int tid = threadIdx.x;
    const int l    = tid & 63;
    const int wid  = tid >> 6;
    const int wr   = wid >> 1;
    const int wc   = wid & 1;
    const int lrow = l & 15;
    const int kg   = l >> 4;

    const int kbase = km * kc;
    const int sr = tid >> 2;
    const int sc = (tid & 3) * 8;
    const unsigned short* gA0 = A  + (size_t)(bm + sr) * lda + sc + kbase;
    const unsigned short* gA1 = A  + (size_t)(bm + sr + 64) * lda + sc + kbase;
    const unsigned short* gB0 = Bw + (size_t)(bn + sr) * ldb + sc + kbase;
    const unsigned short* gB1 = Bw + (size_t)(bn + sr + 64) * ldb + sc + kbase;
    short* lA0 = As + tid * 8;
    short* lA1 = As + tid * 8 + 2048;
    short* lB0 = Bs + tid * 8;
    short* lB1 = Bs + tid * 8 + 2048;

    f32x4 acc[4][4] = {};

    const int aBase = (wr * 64 + lrow) * 32 + kg * 8;
    const int bBase = (wc * 64 + lrow) * 32 + kg * 8;

    for (int k0 = 0; k0 < kc; k0 += 32) {
        __builtin_amdgcn_global_load_lds((const __attribute__((address_space(1))) uint32_t*)(gA0 + k0),
                                         (__attribute__((address_space(3))) uint32_t*)lA0, 16, 0, 0);
        __builtin_amdgcn_global_load_lds((const __attribute__((address_space(1))) uint32_t*)(gA1 + k0),
                                         (__attribute__((address_space(3))) uint32_t*)lA1, 16, 0, 0);
        __builtin_amdgcn_global_load_lds((const __attribute__((address_space(1))) uint32_t*)(gB0 + k0),
                                         (__attribute__((address_space(3))) uint32_t*)lB0, 16, 0, 0);
        __builtin_amdgcn_global_load_lds((const __attribute__((address_space(1))) uint32_t*)(gB1 + k0),
                                         (__attribute__((address_space(3))) uint32_t*)lB1, 16, 0, 0);
        __syncthreads();

        short8 af[4], bf[4];
        #pragma unroll
        for (int i = 0; i < 4; ++i)
            af[i] = *reinterpret_cast<const short8*>(&As[aBase + i * 16 * 32]);
        #pragma unroll
        for (int j = 0; j < 4; ++j)
            bf[j] = *reinterpret_cast<const short8*>(&Bs[bBase + j * 16 * 32]);
        #pragma unroll
        for (int i = 0; i < 4; ++i)
            #pragma unroll
            for (int j = 0; j < 4; ++j)
                acc[i][j] = __builtin_amdgcn_mfma_f32_16x16x32_bf16(af[i], bf[j], acc[i][j], 0, 0, 0);
        __syncthreads();
    }

    float* Pk = P + (size_t)km * T_ * ldc;
    const int rb = kg * 4;
    #pragma unroll
    for (int i = 0; i < 4; ++i) {
        const int row = bm + wr * 64 + i * 16 + rb;
        #pragma unroll
        for (int j = 0; j < 4; ++j) {
            const int col = bn + wc * 64 + j * 16 + lrow;
            #pragma unroll
            for (int rr = 0; rr < 4; ++rr)
                Pk[(size_t)(row + rr) * ldc + col] = acc[i][j][rr];
        }
    }
}

__global__ __launch_bounds__(256)
void reduce_splitk(const float* __restrict__ P, float* __restrict__ C,
                   unsigned short* __restrict__ Cbf, int n4, int S)
{
    int i = blockIdx.x * 256 + threadIdx.x;
    if (i >= n4) return;
    const float4* P4 = reinterpret_cast<const float4*>(P);
    float4 a = P4[i];
    for (int s = 1; s < S; ++s) {
        float4 b = P4[i + (size_t)s * n4];
        a.x += b.x; a.y += b.y; a.z += b.z; a.w += b.w;
    }
    reinterpret_cast<float4*>(C)[i] = a;
    ushort4 o;
    o.x = f2bf1(a.x); o.y = f2bf1(a.y); o.z = f2bf1(a.z); o.w = f2bf1(a.w);
    reinterpret_cast<ushort4*>(Cbf)[i] = o;
}

// ---------------------------------------------------------------------------
// 256x256 8-wave deep-pipelined bf16 GEMM (head + xz projection).
// R13: reverted to the R11 kk-phase variant (best measured: head 303 us);
// the 4-phase split (R12) regressed and the schedule axis is closed
// (5 variants all 25-26% MfmaUtil at K=768).
// ---------------------------------------------------------------------------
#define GBAR() do { asm volatile("" ::: "memory"); \
                    __builtin_amdgcn_s_barrier();  \
                    asm volatile("" ::: "memory"); } while (0)

__global__ __launch_bounds__(512, 2)
void gemm256_bf16(const unsigned short* __restrict__ A, int lda,
                  const unsigned short* __restrict__ Bw, int ldb,
                  float* __restrict__ C, int ldc,
                  const float* __restrict__ bias, int nm, int K)
{
    __shared__ __align__(16) char lds[131072];

    const int nwg = gridDim.x;
    const int bid = blockIdx.x;
    const int q = nwg >> 3, r = nwg & 7;
    const int xcd = bid & 7, idx = bid >> 3;
    const int s = (xcd < r ? xcd * (q + 1) : r * (q + 1) + (xcd - r) * q) + idx;
    const int bm = (s % nm) * 256;
    const int bn = (s / nm) * 256;

    const int tid = threadIdx.x;
    const int l   = tid & 63;
    const int wid = tid >> 6;      // 0..7
    const int wm  = wid >> 2;      // 0..1 (M half)
    const int wn  = wid & 3;       // 0..3 (N quarter)

    const int scb = (tid & 7) * 16;                 // linear LDS byte col
    const int ssw = ((tid >> 3) & 7) << 4;          // row-derived swizzle
    const int scol = (scb ^ ssw) >> 1;              // global col in shorts
    const unsigned short* gA = A  + (size_t)(bm + (tid >> 3)) * lda + scol;
    const unsigned short* gB = Bw + (size_t)(bn + (tid >> 3)) * ldb + scol;
    char* const ldsA = lds + tid * 16;              // + sel*32768 + rr*8192
    char* const ldsB = lds + 65536 + tid * 16;

#define STAGE256(kt, sel)                                                          \
    do {                                                                           \
        const unsigned short* _a = gA + (size_t)(kt) * 64;                         \
        const unsigned short* _b = gB + (size_t)(kt) * 64;                         \
        char* _la = ldsA + (sel) * 32768;                                          \
        char* _lb = ldsB + (sel) * 32768;                                          \
        _Pragma("unroll")                                                          \
        for (int _r = 0; _r < 4; ++_r) {                                           \
            __builtin_amdgcn_global_load_lds(                                      \
                (const __attribute__((address_space(1))) uint32_t*)(_a + (size_t)_r * 64 * lda), \
                (__attribute__((address_space(3))) uint32_t*)(_la + _r * 8192), 16, 0, 0);       \
            __builtin_amdgcn_global_load_lds(                                      \
                (const __attribute__((address_space(1))) uint32_t*)(_b + (size_t)_r * 64 * ldb), \
                (__attribute__((address_space(3))) uint32_t*)(_lb + _r * 8192), 16, 0, 0);       \
        }                                                                          \
    } while (0)

    const int lrow = l & 15;
    const int hi   = (l >> 4) * 16;                 // k-group byte offset 0..48
    const int swl  = (l & 7) << 4;                  // row-derived swizzle (row&7==l&7)
    const int x0   = hi ^ swl;                      // kk=0 swizzled k-byte
    const int x1   = (64 + hi) ^ swl;               // kk=1 swizzled k-byte
    const int aRowB = (wm * 128 + lrow) * 128;      // byte offset of frag row 0
    const int bRowB = (wn * 64 + lrow) * 128;

    f32x4 acc[8][4] = {};

    const int NT = K >> 6;
    STAGE256(0, 0);

    for (int t = 0; t < NT; ++t) {
        const int sel = t & 1;
        if (t + 1 < NT) {
            STAGE256(t + 1, sel ^ 1);
            asm volatile("s_waitcnt vmcnt(8)" ::: "memory");   // tile t landed; t+1 in flight
        } else {
            asm volatile("s_waitcnt vmcnt(0)" ::: "memory");   // tail drain
        }
        GBAR();

        const char* bufA = lds + sel * 32768;
        const char* bufB = lds + 65536 + sel * 32768;

        #pragma unroll
        for (int kk = 0; kk < 2; ++kk) {
            const int xo = kk ? x1 : x0;
            short8 Af[8], Bf[4];
            #pragma unroll
            for (int mi = 0; mi < 8; ++mi)
                Af[mi] = *reinterpret_cast<const short8*>(bufA + aRowB + mi * 16 * 128 + xo);
            #pragma unroll
            for (int ni = 0; ni < 4; ++ni)
                Bf[ni] = *reinterpret_cast<const short8*>(bufB + bRowB + ni * 16 * 128 + xo);
            __builtin_amdgcn_s_setprio(1);
            #pragma unroll
            for (int mi = 0; mi < 8; ++mi)
                #pragma unroll
                for (int ni = 0; ni < 4; ++ni)
                    acc[mi][ni] = __builtin_amdgcn_mfma_f32_16x16x32_bf16(
                        Af[mi], Bf[ni], acc[mi][ni], 0, 0, 0);
            __builtin_amdgcn_s_setprio(0);
        }
        GBAR();
    }

    const int rg = (l >> 4) * 4;
    #pragma unroll
    for (int mf = 0; mf < 8; ++mf) {
        const int row = bm + wm * 128 + mf * 16 + rg;
        #pragma unroll
        for (int nf = 0; nf < 4; ++nf) {
            const int col = bn + wn * 64 + nf * 16 + lrow;
            const float bb = bias ? bias[col] : 0.f;
            #pragma unroll
            for (int rr2 = 0; rr2 < 4; ++rr2)
                C[(size_t)(row + rr2) * ldc + col] = acc[mf][nf][rr2] + bb;
        }
    }
#undef STAGE256
}

// ---------------------------------------------------------------------------
// Depthwise causal conv (K=4) + bias + SiLU -> u fp32 + u bf16.
// R13: float4-vectorized (4 channels/thread, fp32 datapath unchanged —
// unlike R8's failed 8-wide bf16 version). Tap weights loaded once as
// float4 per channel; all loads/stores 16B coalesced.
// ---------------------------------------------------------------------------
__global__ __launch_bounds__(256)
void conv_silu_kernel(const float* __restrict__ xz, const float* __restrict__ cw,
                      const float* __restrict__ cb, float* __restrict__ u,
                      unsigned short* __restrict__ u_bf)
{
    int idx = blockIdx.x * 256 + threadIdx.x;       // over T*ED/4
    if (idx >= T_ * ED_ / 4) return;
    const int epb = ED_ / 4;                        // 384
    int t  = idx / epb;
    int e0 = (idx - t * epb) * 4;
    int l  = t % L_;

    const float4 w0 = *reinterpret_cast<const float4*>(&cw[(e0 + 0) * KC_]);
    const float4 w1 = *reinterpret_cast<const float4*>(&cw[(e0 + 1) * KC_]);
    const float4 w2 = *reinterpret_cast<const float4*>(&cw[(e0 + 2) * KC_]);
    const float4 w3 = *reinterpret_cast<const float4*>(&cw[(e0 + 3) * KC_]);
    const float t0a[4] = {w0.x, w0.y, w0.z, w0.w};
    const float t1a[4] = {w1.x, w1.y, w1.z, w1.w};
    const float t2a[4] = {w2.x, w2.y, w2.z, w2.w};
    const float t3a[4] = {w3.x, w3.y, w3.z, w3.w};

    float4 acc = *reinterpret_cast<const float4*>(&cb[e0]);
    #pragma unroll
    for (int k = 0; k < KC_; ++k) {
        int ll = l - (KC_ - 1) + k;
        if (ll >= 0) {
            float4 v = *reinterpret_cast<const float4*>(
                &xz[(size_t)(t - (KC_ - 1) + k) * (2 * ED_) + e0]);
            acc.x = fmaf(t0a[k], v.x, acc.x);
            acc.y = fmaf(t1a[k], v.y, acc.y);
            acc.z = fmaf(t2a[k], v.z, acc.z);
            acc.w = fmaf(t3a[k], v.w, acc.w);
        }
    }
    float4 o;
    o.x = siluf(acc.x); o.y = siluf(acc.y); o.z = siluf(acc.z); o.w = siluf(acc.w);
    *reinterpret_cast<float4*>(&u[(size_t)t * ED_ + e0]) = o;
    ushort4 ob;
    ob.x = f2bf1(o.x); ob.y = f2bf1(o.y); ob.z = f2bf1(o.z); ob.w = f2bf1(o.w);
    *reinterpret_cast<ushort4*>(&u_bf[(size_t)t * ED_ + e0]) = ob;
}

// ---------------------------------------------------------------------------
// Chunked selective scan, e-lane layout (round-11 win: coalesced loads,
// states in registers, no shuffles)
// ---------------------------------------------------------------------------
__global__ __launch_bounds__(256)
void scanA_kernel(const float* __restrict__ delta,
                  const float* __restrict__ dbc,
                  const float* __restrict__ u,
                  const float* __restrict__ A_log,
                  float* __restrict__ hend,
                  float* __restrict__ Pcum)
{
    const int b = blockIdx.z;
    const int c = blockIdx.y;
    const int e = blockIdx.x * 256 + threadIdx.x;

    float Aen[16], h[16], P[16];
    #pragma unroll
    for (int n = 0; n < NS_; ++n) {
        Aen[n] = -__expf(A_log[e * NS_ + n]);
        h[n] = 0.f; P[n] = 1.f;
    }

    const int t0 = b * L_ + c * SCH_;
    #pragma unroll 2
    for (int l = 0; l < SCH_; ++l) {
        const size_t t = (size_t)(t0 + l);
        const float d  = delta[t * ED_ + e];
        const float uu = u[t * ED_ + e];
        const float du = d * uu;
        const float4* Bv = reinterpret_cast<const float4*>(&dbc[t * DBCP_ + DTR_]);
        #pragma unroll
        for (int g = 0; g < 4; ++g) {
            const float4 Bg = Bv[g];
            const float Bx[4] = {Bg.x, Bg.y, Bg.z, Bg.w};
            #pragma unroll
            for (int j = 0; j < 4; ++j) {
                const int n = g * 4 + j;
                const float a = __expf(d * Aen[n]);
                h[n] = fmaf(a, h[n], du * Bx[j]);
                P[n] *= a;
            }
        }
    }
    const size_t base = ((size_t)(b * NCH_ + c) * 16) * ED_ + e;
    #pragma unroll
    for (int n = 0; n < NS_; ++n) {
        hend[base + (size_t)n * ED_] = h[n];
        Pcum[base + (size_t)n * ED_] = P[n];
    }
}

// carry pass: thread = (b, n, e); loops chunks; all loads/stores e-coalesced
__global__ __launch_bounds__(256)
void scanB2_kernel(const float* __restrict__ hend,
                   const float* __restrict__ Pcum,
                   float* __restrict__ carry)
{
    const int i = blockIdx.x * 256 + threadIdx.x;   // over B*16*ED
    const int e = i % ED_;
    const int n = (i / ED_) % 16;
    const int b = i / (16 * ED_);
    float cr = 0.f;
    #pragma unroll 4
    for (int c = 0; c < NCH_; ++c) {
        const size_t idx = (((size_t)(b * NCH_ + c) * 16) + n) * ED_ + e;
        carry[idx] = cr;
        cr = fmaf(Pcum[idx], cr, hend[idx]);
    }
}

__global__ __launch_bounds__(256)
void scanC_kernel(const float* __restrict__ delta,
                  const float* __restrict__ dbc,
                  const float* __restrict__ u,
                  const float* __restrict__ xz,
                  const float* __restrict__ A_log,
                  const float* __restrict__ Dp,
                  const float* __restrict__ carry,
                  unsigned short* __restrict__ y_bf)
{
    const int b = blockIdx.z;
    const int c = blockIdx.y;
    const int e = blockIdx.x * 256 + threadIdx.x;

    const float De = Dp[e];
    float Aen[16], h[16];
    const size_t cbase = ((size_t)(b * NCH_ + c) * 16) * ED_ + e;
    #pragma unroll
    for (int n = 0; n < NS_; ++n) {
        Aen[n] = -__expf(A_log[e * NS_ + n]);
        h[n] = carry[cbase + (size_t)n * ED_];
    }

    const int t0 = b * L_ + c * SCH_;
    #pragma unroll 2
    for (int l = 0; l < SCH_; ++l) {
        const size_t t = (size_t)(t0 + l);
        const float d  = delta[t * ED_ + e];
        const float uu = u[t * ED_ + e];
        const float du = d * uu;
        const float4* Bv = reinterpret_cast<const float4*>(&dbc[t * DBCP_ + DTR_]);
        const float4* Cv = reinterpret_cast<const float4*>(&dbc[t * DBCP_ + DTR_ + NS_]);
        float p = 0.f;
        #pragma unroll
        for (int g = 0; g < 4; ++g) {
            const float4 Bg = Bv[g];
            const float4 Cg = Cv[g];
            const float Bx[4] = {Bg.x, Bg.y, Bg.z, Bg.w};
            const float Cx[4] = {Cg.x, Cg.y, Cg.z, Cg.w};
            #pragma unroll
            for (int j = 0; j < 4; ++j) {
                const int n = g * 4 + j;
                const float a = __expf(d * Aen[n]);
                h[n] = fmaf(a, h[n], du * Bx[j]);
                p = fmaf(h[n], Cx[j], p);
            }
        }
        const float ys = p + uu * De;
        const float rr = xz[t * (2 * ED_) + ED_ + e];
        y_bf[t * ED_ + e] = f2bf1(ys * siluf(rr));
    }
}

// ---------------------------------------------------------------------------
// LayerNorm over DM, in place; also emits bf16
// ---------------------------------------------------------------------------
__global__ __launch_bounds__(256)
void ln_kernel(float* __restrict__ x, const float* __restrict__ g,
               const float* __restrict__ bta, unsigned short* __restrict__ x_bf)
{
    const int t = blockIdx.x;
    float* xr = x + (size_t)t * DM_;
    unsigned short* xb = x_bf + (size_t)t * DM_;
    const int tid = threadIdx.x;

    float v0 = xr[tid], v1 = xr[tid + 256], v2 = xr[tid + 512];
    float s  = v0 + v1 + v2;
    float sq = v0 * v0 + v1 * v1 + v2 * v2;

    __shared__ float s1[256], s2[256];
    s1[tid] = s; s2[tid] = sq;
    __syncthreads();
    for (int off = 128; off > 0; off >>= 1) {
        if (tid < off) { s1[tid] += s1[tid + off]; s2[tid] += s2[tid + off]; }
        __syncthreads();
    }
    const float mu  = s1[0] * (1.f / DM_);
    const float var = s2[0] * (1.f / DM_) - mu * mu;
    const float rs  = rsqrtf(var + 1e-5f);

    float o0 = (v0 - mu) * rs * g[tid]       + bta[tid];
    float o1 = (v1 - mu) * rs * g[tid + 256] + bta[tid + 256];
    float o2 = (v2 - mu) * rs * g[tid + 512] + bta[tid + 512];
    xr[tid] = o0;       xb[tid] = f2bf1(o0);
    xr[tid + 256] = o1; xb[tid + 256] = f2bf1(o1);
    xr[tid + 512] = o2; xb[tid + 512] = f2bf1(o2);
}

// ---------------------------------------------------------------------------
extern "C" void kernel_launch(void* const* d_in, const int* in_sizes, int n_in,
                              void* d_out, int out_size, void* d_ws, size_t ws_size,
                              hipStream_t stream)
{
    const int*   ids       = (const int*)  d_in[0];
    const float* emb       = (const float*)d_in[1];
    const float* in_proj_w = (const float*)d_in[2];
    const float* conv_w    = (const float*)d_in[3];
    const float* conv_b    = (const float*)d_in[4];
    const float* x_proj_w  = (const float*)d_in[5];
    const float* dt_proj_w = (const float*)d_in[6];
    const float* dt_proj_b = (const float*)d_in[7];
    const float* A_log     = (const float*)d_in[8];
    const float* Dp        = (const float*)d_in[9];
    const float* out_proj_w= (const float*)d_in[10];
    const float* ln_g      = (const float*)d_in[11];
    const float* ln_b      = (const float*)d_in[12];
    const float* head_w    = (const float*)d_in[13];
    const float* head_b    = (const float*)d_in[14];
    float* out = (float*)d_out;

    // fp32 workspace
    float* ws    = (float*)d_ws;
    float* x     = ws;                              // T*DM
    float* xz    = x     + (size_t)T_ * DM_;        // T*2ED
    float* u     = xz    + (size_t)T_ * 2 * ED_;    // T*ED
    float* dbc   = u     + (size_t)T_ * ED_;        // T*128 (padded)
    float* delta = dbc   + (size_t)T_ * DBCP_;      // T*ED
    float* hend  = delta + (size_t)T_ * ED_;        // B*NCH*16*ED
    float* Pcum  = hend  + (size_t)B_ * NCH_ * 16 * ED_;
    float* carry = Pcum  + (size_t)B_ * NCH_ * 16 * ED_;
    float* part  = carry + (size_t)B_ * NCH_ * 16 * ED_;  // 4*T*DM floats
    // bf16 workspace
    unsigned short* bf = (unsigned short*)(part + (size_t)4 * T_ * DM_);
    unsigned short* x_bf    = bf;                                 // T*DM
    unsigned short* u_bf    = x_bf    + (size_t)T_ * DM_;         // T*ED
    unsigned short* y_bf    = u_bf    + (size_t)T_ * ED_;         // T*ED
    unsigned short* dbc_bf  = y_bf    + (size_t)T_ * ED_;         // T*128
    unsigned short* inw_bf  = dbc_bf  + (size_t)T_ * DBCP_;       // NL*2ED*DM
    unsigned short* outw_bf = inw_bf  + (size_t)NL_ * 2 * ED_ * DM_;  // NL*DM*ED
    unsigned short* wx_bf   = outw_bf + (size_t)NL_ * DM_ * ED_;      // NL*128*ED
    unsigned short* wdt_bf  = wx_bf   + (size_t)NL_ * 128 * ED_;      // NL*ED*64
    unsigned short* hw_bf   = wdt_bf  + (size_t)NL_ * ED_ * 64;       // V*DM

    // ---- upfront: embedding + ALL weight conversions in one dispatch
    embed_kernel<<<(T_ * DM_ + 255) / 256, 256, 0, stream>>>(ids, emb, x_bf);
    prep_kernel<<<PREP_NB, 256, 0, stream>>>(
        in_proj_w, inw_bf, out_proj_w, outw_bf, x_proj_w, wx_bf,
        dt_proj_w, wdt_bf, head_w, hw_bf);

    for (int i = 0; i < NL_; ++i) {
        const unsigned short* w_in  = inw_bf  + (size_t)i * 2 * ED_ * DM_;
        const float*          cw    = conv_w  + (size_t)i * ED_ * KC_;
        const float*          cb    = conv_b  + (size_t)i * ED_;
        const unsigned short* w_x   = wx_bf   + (size_t)i * 128 * ED_;
        const unsigned short* w_dt  = wdt_bf  + (size_t)i * ED_ * 64;
        const float*          b_dt  = dt_proj_b + (size_t)i * ED_;
        const float*          al    = A_log   + (size_t)i * ED_ * NS_;
        const float*          dpar  = Dp      + (size_t)i * ED_;
        const unsigned short* w_out = outw_bf + (size_t)i * DM_ * ED_;

        // xz = x @ w_in^T  (4096 x 3072, K=768) — 256² deep-pipelined structure
        gemm256_bf16<<<(T_/256) * (2*ED_/256), 512, 0, stream>>>(
            x_bf, DM_, w_in, DM_, xz, 2 * ED_, nullptr, T_/256, DM_);

        // u = silu(depthwise causal conv + cb)  (+ bf16), float4 vectorized
        conv_silu_kernel<<<(T_ * ED_ / 4 + 255) / 256, 256, 0, stream>>>(
            xz, cw, cb, u, u_bf);

        // dbc = u @ w_x_pad^T  (4096 x 128, K=1536) — split-K S=8 (32->256 blocks)
        gemm_splitk_bf16<<<(T_/128) * 1 * 8, 256, 0, stream>>>(
            u_bf, ED_, w_x, ED_, part, DBCP_, T_/128, 8, ED_/8);
        reduce_splitk<<<(T_ * DBCP_ / 4 + 255) / 256, 256, 0, stream>>>(
            part, dbc, dbc_bf, T_ * DBCP_ / 4, 8);

        // delta = softplus(dbc[:, :64] @ w_dt_pad^T + b_dt)  (4096 x 1536, K=64)
        gemm_bf16<1, false><<<(T_/128) * (ED_/128), 256, 0, stream>>>(
            dbc_bf, DBCP_, w_dt, 64, delta, nullptr, ED_, b_dt, T_/128, 64);

        // chunked selective scan + gating -> y_bf (e-lane layout, 3 passes)
        scanA_kernel<<<dim3(ED_ / 256, NCH_, B_), 256, 0, stream>>>(
            delta, dbc, u, al, hend, Pcum);
        scanB2_kernel<<<(B_ * 16 * ED_) / 256, 256, 0, stream>>>(hend, Pcum, carry);
        scanC_kernel<<<dim3(ED_ / 256, NCH_, B_), 256, 0, stream>>>(
            delta, dbc, u, xz, al, dpar, carry, y_bf);

        // x = y @ w_out^T  (4096 x 768, K=1536) — split-K S=4 (192->768 blocks)
        gemm_splitk_bf16<<<(T_/128) * (DM_/128) * 4, 256, 0, stream>>>(
            y_bf, ED_, w_out, ED_, part, DM_, T_/128, 4, ED_/4);
        reduce_splitk<<<(T_ * DM_ / 4 + 255) / 256, 256, 0, stream>>>(
            part, x, x_bf, T_ * DM_ / 4, 4);
    }

    // LayerNorm (fp32 in place + bf16), then head with the 256² deep-pipelined GEMM
    ln_kernel<<<T_, 256, 0, stream>>>(x, ln_g, ln_b, x_bf);
    gemm256_bf16<<<(T_/256) * (V_/256), 512, 0, stream>>>(
        x_bf, DM_, hw_bf, DM_, out, V_, head_b, T_/256, DM_);
}

// Round 14
// 1101.697 us; speedup vs baseline: 1.0467x; 1.0154x over previous
//
#include <hip/hip_runtime.h>
#include <math.h>
#include <stdint.h>

#define B_   2
#define L_   2048
#define T_   (B_ * L_)      // 4096 tokens
#define V_   32000
#define DM_  768
#define NL_  4
#define NS_  16             // d_state
#define KC_  4              // d_conv
#define ED_  1536           // d_inner
#define DTR_ 48             // dt_rank
#define DBCP_ 128           // padded dbc row stride (was 80)
#define NCH_ 64             // scan chunks (e-lane layout needs more chunks for occupancy)
#define SCH_ (L_ / NCH_)    // chunk length = 32

typedef __attribute__((ext_vector_type(8))) short short8;
typedef __attribute__((ext_vector_type(4))) float f32x4;

__device__ __forceinline__ float siluf(float x) { return x / (1.f + __expf(-x)); }

__device__ __forceinline__ unsigned short f2bf1(float f) {
    union { float f; uint32_t u; } c; c.f = f;
    uint32_t u = c.u;
    uint32_t r = (u + 0x7FFFu + ((u >> 16) & 1u)) >> 16;   // RNE
    return (unsigned short)r;
}

// ---------------------------------------------------------------------------
// Merged upfront weight conversion (one dispatch replaces 5)
// ---------------------------------------------------------------------------
#define PREP_B0 9216
#define PREP_B1 13824
#define PREP_B2 14592
#define PREP_B3 14976
#define PREP_NB 38976

__global__ __launch_bounds__(256)
void prep_kernel(const float* __restrict__ inw, unsigned short* __restrict__ inw_bf,
                 const float* __restrict__ outw, unsigned short* __restrict__ outw_bf,
                 const float* __restrict__ wx, unsigned short* __restrict__ wx_bf,
                 const float* __restrict__ wdt, unsigned short* __restrict__ wdt_bf,
                 const float* __restrict__ hw, unsigned short* __restrict__ hw_bf)
{
    const int b = blockIdx.x;
    const int tid = threadIdx.x;

    if (b < PREP_B0) {                       // in_proj plain f2bf
        int i = b * 256 + tid;               // over NL*2ED*DM/4
        float4 v = reinterpret_cast<const float4*>(inw)[i];
        ushort4 o;
        o.x = f2bf1(v.x); o.y = f2bf1(v.y); o.z = f2bf1(v.z); o.w = f2bf1(v.w);
        reinterpret_cast<ushort4*>(inw_bf)[i] = o;
    } else if (b < PREP_B1) {                // out_proj plain f2bf
        int i = (b - PREP_B0) * 256 + tid;   // over NL*DM*ED/4
        float4 v = reinterpret_cast<const float4*>(outw)[i];
        ushort4 o;
        o.x = f2bf1(v.x); o.y = f2bf1(v.y); o.z = f2bf1(v.z); o.w = f2bf1(v.w);
        reinterpret_cast<ushort4*>(outw_bf)[i] = o;
    } else if (b < PREP_B2) {                // x_proj pad
        int i = (b - PREP_B1) * 256 + tid;   // over NL*128*ED/4
        int e4 = i * 4;
        int l  = e4 / (128 * ED_);
        int r  = (e4 / ED_) % 128;
        int c  = e4 % ED_;
        ushort4 o;
        if (r < 80) {
            const float* s = wx + (size_t)l * 80 * ED_ + (size_t)r * ED_ + c;
            float4 v = *reinterpret_cast<const float4*>(s);
            o.x = f2bf1(v.x); o.y = f2bf1(v.y); o.z = f2bf1(v.z); o.w = f2bf1(v.w);
        } else {
            o.x = o.y = o.z = o.w = 0;
        }
        reinterpret_cast<ushort4*>(wx_bf)[i] = o;
    } else if (b < PREP_B3) {                // dt_proj pad
        int i = (b - PREP_B2) * 256 + tid;   // over NL*ED*64/4
        int e4 = i * 4;
        int l  = e4 / (ED_ * 64);
        int e  = (e4 / 64) % ED_;
        int k  = e4 % 64;
        ushort4 o;
        if (k < DTR_) {    // 4-groups never straddle 48
            const float* s = wdt + (size_t)l * ED_ * DTR_ + (size_t)e * DTR_ + k;
            float4 v = *reinterpret_cast<const float4*>(s);
            o.x = f2bf1(v.x); o.y = f2bf1(v.y); o.z = f2bf1(v.z); o.w = f2bf1(v.w);
        } else {
            o.x = o.y = o.z = o.w = 0;
        }
        reinterpret_cast<ushort4*>(wdt_bf)[i] = o;
    } else {                                 // head_w plain f2bf
        int i = (b - PREP_B3) * 256 + tid;   // over V*DM/4
        float4 v = reinterpret_cast<const float4*>(hw)[i];
        ushort4 o;
        o.x = f2bf1(v.x); o.y = f2bf1(v.y); o.z = f2bf1(v.z); o.w = f2bf1(v.w);
        reinterpret_cast<ushort4*>(hw_bf)[i] = o;
    }
}

// ---------------------------------------------------------------------------
// Embedding gather -> x bf16 only
// ---------------------------------------------------------------------------
__global__ __launch_bounds__(256)
void embed_kernel(const int* __restrict__ ids, const float* __restrict__ emb,
                  unsigned short* __restrict__ x_bf)
{
    int i = blockIdx.x * 256 + threadIdx.x;
    if (i >= T_ * DM_) return;
    int t = i / DM_;
    int d = i - t * DM_;
    x_bf[i] = f2bf1(emb[(size_t)ids[t] * DM_ + d]);
}

// ---------------------------------------------------------------------------
// bf16 MFMA NT GEMM (m97 structure, generalized)
// ---------------------------------------------------------------------------
template<int ACT, bool DUAL>
__global__ __launch_bounds__(256)
void gemm_bf16(const unsigned short* __restrict__ A, int lda,
               const unsigned short* __restrict__ Bw, int ldb,
               float* __restrict__ C, unsigned short* __restrict__ Cbf, int ldc,
               const float* __restrict__ bias, int nm, int K)
{
    __shared__ short As[128 * 32];
    __shared__ short Bs[128 * 32];

    const int nwg = gridDim.x;
    const int bid = blockIdx.x;
    const int q = nwg >> 3, r = nwg & 7;
    const int xcd = bid & 7, idx = bid >> 3;
    const int s = (xcd < r ? xcd * (q + 1) : r * (q + 1) + (xcd - r) * q) + idx;
    const int bm = (s % nm) * 128;
    const int bn = (s / nm) * 128;

    const int tid = threadIdx.x;
    const int l    = tid & 63;
    const int wid  = tid >> 6;
    const int wr   = wid >> 1;
    const int wc   = wid & 1;
    const int lrow = l & 15;
    const int kg   = l >> 4;

    const int sr = tid >> 2;
    const int sc = (tid & 3) * 8;
    const unsigned short* gA0 = A  + (size_t)(bm + sr) * lda + sc;
    const unsigned short* gA1 = A  + (size_t)(bm + sr + 64) * lda + sc;
    const unsigned short* gB0 = Bw + (size_t)(bn + sr) * ldb + sc;
    const unsigned short* gB1 = Bw + (size_t)(bn + sr + 64) * ldb + sc;
    short* lA0 = As + tid * 8;
    short* lA1 = As + tid * 8 + 2048;
    short* lB0 = Bs + tid * 8;
    short* lB1 = Bs + tid * 8 + 2048;

    f32x4 acc[4][4] = {};

    const int aBase = (wr * 64 + lrow) * 32 + kg * 8;
    const int bBase = (wc * 64 + lrow) * 32 + kg * 8;

    for (int k0 = 0; k0 < K; k0 += 32) {
        __builtin_amdgcn_global_load_lds((const __attribute__((address_space(1))) uint32_t*)(gA0 + k0),
                                         (__attribute__((address_space(3))) uint32_t*)lA0, 16, 0, 0);
        __builtin_amdgcn_global_load_lds((const __attribute__((address_space(1))) uint32_t*)(gA1 + k0),
                                         (__attribute__((address_space(3))) uint32_t*)lA1, 16, 0, 0);
        __builtin_amdgcn_global_load_lds((const __attribute__((address_space(1))) uint32_t*)(gB0 + k0),
                                         (__attribute__((address_space(3))) uint32_t*)lB0, 16, 0, 0);
        __builtin_amdgcn_global_load_lds((const __attribute__((address_space(1))) uint32_t*)(gB1 + k0),
                                         (__attribute__((address_space(3))) uint32_t*)lB1, 16, 0, 0);
        __syncthreads();

        short8 af[4], bf[4];
        #pragma unroll
        for (int i = 0; i < 4; ++i)
            af[i] = *reinterpret_cast<const short8*>(&As[aBase + i * 16 * 32]);
        #pragma unroll
        for (int j = 0; j < 4; ++j)
            bf[j] = *reinterpret_cast<const short8*>(&Bs[bBase + j * 16 * 32]);
        #pragma unroll
        for (int i = 0; i < 4; ++i)
            #pragma unroll
            for (int j = 0; j < 4; ++j)
                acc[i][j] = __builtin_amdgcn_mfma_f32_16x16x32_bf16(af[i], bf[j], acc[i][j], 0, 0, 0);
        __syncthreads();
    }

    const int rb = kg * 4;
    #pragma unroll
    for (int i = 0; i < 4; ++i) {
        const int row = bm + wr * 64 + i * 16 + rb;
        #pragma unroll
        for (int j = 0; j < 4; ++j) {
            const int col = bn + wc * 64 + j * 16 + lrow;
            const float b = bias ? bias[col] : 0.f;
            #pragma unroll
            for (int rr = 0; rr < 4; ++rr) {
                float v = acc[i][j][rr] + b;
                if (ACT == 1) v = fmaxf(v, 0.f) + __logf(1.f + __expf(-fabsf(v)));  // softplus
                C[(size_t)(row + rr) * ldc + col] = v;
                if (DUAL) Cbf[(size_t)(row + rr) * ldc + col] = f2bf1(v);
            }
        }
    }
}

// ---------------------------------------------------------------------------
// Split-K m97 GEMM + reduction (round-10 win: co-residency for long-K GEMMs)
// ---------------------------------------------------------------------------
__global__ __launch_bounds__(256)
void gemm_splitk_bf16(const unsigned short* __restrict__ A, int lda,
                      const unsigned short* __restrict__ Bw, int ldb,
                      float* __restrict__ P, int ldc, int nm, int S, int kc)
{
    __shared__ short As[128 * 32];
    __shared__ short Bs[128 * 32];

    const int nwg = gridDim.x;
    const int bid = blockIdx.x;
    const int q = nwg >> 3, r = nwg & 7;
    const int xcd = bid & 7, idx = bid >> 3;
    const int s = (xcd < r ? xcd * (q + 1) : r * (q + 1) + (xcd - r) * q) + idx;
    const int ntile = nwg / S;
    const int bt = s % ntile;
    const int km = s / ntile;
    const int bm = (bt % nm) * 128;
    const int bn = (bt / nm) * 128;

    const int tid = threadIdx.x;
    const int l    = tid & 63;
    const int wid  = tid >> 6;
    const int wr   = wid >> 1;
    const int wc   = wid & 1;
    const int lrow = l & 15;
    const int kg   = l >> 4;

    const int kbase = km * kc;
    const int sr = tid >> 2;
    const int sc = (tid & 3) * 8;
    const unsigned short* gA0 = A  + (size_t)(bm + sr) * lda + sc + kbase;
    const unsigned short* gA1 = A  + (size_t)(bm + sr + 64) * lda + sc + kbase;
    const unsigned short* gB0 = Bw + (size_t)(bn + sr) * ldb + sc + kbase;
    const unsigned short* gB1 = Bw + (size_t)(bn + sr + 64) * ldb + sc + kbase;
    short* lA0 = As + tid * 8;
    short* lA1 = As + tid * 8 + 2048;
    short* lB0 = Bs + tid * 8;
    short* lB1 = Bs + tid * 8 + 2048;

    f32x4 acc[4][4] = {};

    const int aBase = (wr * 64 + lrow) * 32 + kg * 8;
    const int bBase = (wc * 64 + lrow) * 32 + kg * 8;

    for (int k0 = 0; k0 < kc; k0 += 32) {
        __builtin_amdgcn_global_load_lds((const __attribute__((address_space(1))) uint32_t*)(gA0 + k0),
                                         (__attribute__((address_space(3))) uint32_t*)lA0, 16, 0, 0);
        __builtin_amdgcn_global_load_lds((const __attribute__((address_space(1))) uint32_t*)(gA1 + k0),
                                         (__attribute__((address_space(3))) uint32_t*)lA1, 16, 0, 0);
        __builtin_amdgcn_global_load_lds((const __attribute__((address_space(1))) uint32_t*)(gB0 + k0),
                                         (__attribute__((address_space(3))) uint32_t*)lB0, 16, 0, 0);
        __builtin_amdgcn_global_load_lds((const __attribute__((address_space(1))) uint32_t*)(gB1 + k0),
                                         (__attribute__((address_space(3))) uint32_t*)lB1, 16, 0, 0);
        __syncthreads();

        short8 af[4], bf[4];
        #pragma unroll
        for (int i = 0; i < 4; ++i)
            af[i] = *reinterpret_cast<const short8*>(&As[aBase + i * 16 * 32]);
        #pragma unroll
        for (int j = 0; j < 4; ++j)
            bf[j] = *reinterpret_cast<const short8*>(&Bs[bBase + j * 16 * 32]);
        #pragma unroll
        for (int i = 0; i < 4; ++i)
            #pragma unroll
            for (int j = 0; j < 4; ++j)
                acc[i][j] = __builtin_amdgcn_mfma_f32_16x16x32_bf16(af[i], bf[j], acc[i][j], 0, 0, 0);
        __syncthreads();
    }

    float* Pk = P + (size_t)km * T_ * ldc;
    const int rb = kg * 4;
    #pragma unroll
    for (int i = 0; i < 4; ++i) {
        const int row = bm + wr * 64 + i * 16 + rb;
        #pragma unroll
        for (int j = 0; j < 4; ++j) {
            const int col = bn + wc * 64 + j * 16 + lrow;
            #pragma unroll
            for (int rr = 0; rr < 4; ++rr)
                Pk[(size_t)(row + rr) * ldc + col] = acc[i][j][rr];
        }
    }
}

__global__ __launch_bounds__(256)
void reduce_splitk(const float* __restrict__ P, float* __restrict__ C,
                   unsigned short* __restrict__ Cbf, int n4, int S)
{
    int i = blockIdx.x * 256 + threadIdx.x;
    if (i >= n4) return;
    const float4* P4 = reinterpret_cast<const float4*>(P);
    float4 a = P4[i];
    for (int s = 1; s < S; ++s) {
        float4 b = P4[i + (size_t)s * n4];
        a.x += b.x; a.y += b.y; a.z += b.z; a.w += b.w;
    }
    reinterpret_cast<float4*>(C)[i] = a;
    ushort4 o;
    o.x = f2bf1(a.x); o.y = f2bf1(a.y); o.z = f2bf1(a.z); o.w = f2bf1(a.w);
    reinterpret_cast<ushort4*>(Cbf)[i] = o;
}

// ---------------------------------------------------------------------------
// 256x256 8-wave deep-pipelined bf16 GEMM (head + xz projection).
// Main loop: R11 kk-phase variant (best measured). R14: epilogue rewritten
// as LDS-transposed float4 stores — the old path issued 128 scattered
// global_store_dword/lane-group (64B row segments); new path scatters acc
// into a per-wave LDS tile (stride 68 floats: 16B-aligned rows, 2-way banks
// = free) then stores 16-lane x float4 = 256B contiguous runs. Per-wave
// regions disjoint -> no barriers; main-loop LDS safely reused post-loop.
// ---------------------------------------------------------------------------
#define GBAR() do { asm volatile("" ::: "memory"); \
                    __builtin_amdgcn_s_barrier();  \
                    asm volatile("" ::: "memory"); } while (0)

__global__ __launch_bounds__(512, 2)
void gemm256_bf16(const unsigned short* __restrict__ A, int lda,
                  const unsigned short* __restrict__ Bw, int ldb,
                  float* __restrict__ C, int ldc,
                  const float* __restrict__ bias, int nm, int K)
{
    __shared__ __align__(16) char lds[131072];

    const int nwg = gridDim.x;
    const int bid = blockIdx.x;
    const int q = nwg >> 3, r = nwg & 7;
    const int xcd = bid & 7, idx = bid >> 3;
    const int s = (xcd < r ? xcd * (q + 1) : r * (q + 1) + (xcd - r) * q) + idx;
    const int bm = (s % nm) * 256;
    const int bn = (s / nm) * 256;

    const int tid = threadIdx.x;
    const int l   = tid & 63;
    const int wid = tid >> 6;      // 0..7
    const int wm  = wid >> 2;      // 0..1 (M half)
    const int wn  = wid & 3;       // 0..3 (N quarter)

    const int scb = (tid & 7) * 16;                 // linear LDS byte col
    const int ssw = ((tid >> 3) & 7) << 4;          // row-derived swizzle
    const int scol = (scb ^ ssw) >> 1;              // global col in shorts
    const unsigned short* gA = A  + (size_t)(bm + (tid >> 3)) * lda + scol;
    const unsigned short* gB = Bw + (size_t)(bn + (tid >> 3)) * ldb + scol;
    char* const ldsA = lds + tid * 16;              // + sel*32768 + rr*8192
    char* const ldsB = lds + 65536 + tid * 16;

#define STAGE256(kt, sel)                                                          \
    do {                                                                           \
        const unsigned short* _a = gA + (size_t)(kt) * 64;                         \
        const unsigned short* _b = gB + (size_t)(kt) * 64;                         \
        char* _la = ldsA + (sel) * 32768;                                          \
        char* _lb = ldsB + (sel) * 32768;                                          \
        _Pragma("unroll")                                                          \
        for (int _r = 0; _r < 4; ++_r) {                                           \
            __builtin_amdgcn_global_load_lds(                                      \
                (const __attribute__((address_space(1))) uint32_t*)(_a + (size_t)_r * 64 * lda), \
                (__attribute__((address_space(3))) uint32_t*)(_la + _r * 8192), 16, 0, 0);       \
            __builtin_amdgcn_global_load_lds(                                      \
                (const __attribute__((address_space(1))) uint32_t*)(_b + (size_t)_r * 64 * ldb), \
                (__attribute__((address_space(3))) uint32_t*)(_lb + _r * 8192), 16, 0, 0);       \
        }                                                                          \
    } while (0)

    const int lrow = l & 15;
    const int kg   = l >> 4;                        // 0..3
    const int hi   = kg * 16;                       // k-group byte offset 0..48
    const int swl  = (l & 7) << 4;                  // row-derived swizzle (row&7==l&7)
    const int x0   = hi ^ swl;                      // kk=0 swizzled k-byte
    const int x1   = (64 + hi) ^ swl;               // kk=1 swizzled k-byte
    const int aRowB = (wm * 128 + lrow) * 128;      // byte offset of frag row 0
    const int bRowB = (wn * 64 + lrow) * 128;

    f32x4 acc[8][4] = {};

    const int NT = K >> 6;
    STAGE256(0, 0);

    for (int t = 0; t < NT; ++t) {
        const int sel = t & 1;
        if (t + 1 < NT) {
            STAGE256(t + 1, sel ^ 1);
            asm volatile("s_waitcnt vmcnt(8)" ::: "memory");   // tile t landed; t+1 in flight
        } else {
            asm volatile("s_waitcnt vmcnt(0)" ::: "memory");   // tail drain
        }
        GBAR();

        const char* bufA = lds + sel * 32768;
        const char* bufB = lds + 65536 + sel * 32768;

        #pragma unroll
        for (int kk = 0; kk < 2; ++kk) {
            const int xo = kk ? x1 : x0;
            short8 Af[8], Bf[4];
            #pragma unroll
            for (int mi = 0; mi < 8; ++mi)
                Af[mi] = *reinterpret_cast<const short8*>(bufA + aRowB + mi * 16 * 128 + xo);
            #pragma unroll
            for (int ni = 0; ni < 4; ++ni)
                Bf[ni] = *reinterpret_cast<const short8*>(bufB + bRowB + ni * 16 * 128 + xo);
            __builtin_amdgcn_s_setprio(1);
            #pragma unroll
            for (int mi = 0; mi < 8; ++mi)
                #pragma unroll
                for (int ni = 0; ni < 4; ++ni)
                    acc[mi][ni] = __builtin_amdgcn_mfma_f32_16x16x32_bf16(
                        Af[mi], Bf[ni], acc[mi][ni], 0, 0, 0);
            __builtin_amdgcn_s_setprio(0);
        }
        GBAR();
    }

    // ---- epilogue: LDS-transposed, float4-coalesced C stores
    {
        float* lw = reinterpret_cast<float*>(lds) + (size_t)wid * (16 * 68);
        const int colb = 4 * lrow;                          // 0..60
        const int col  = bn + wn * 64 + colb;
        float4 b4 = make_float4(0.f, 0.f, 0.f, 0.f);
        if (bias) b4 = *reinterpret_cast<const float4*>(&bias[col]);

        #pragma unroll
        for (int mf = 0; mf < 8; ++mf) {
            // scatter this 16x64 stripe into LDS [r][c], r = 4*kg+rr2, c = nf*16+lrow
            #pragma unroll
            for (int nf = 0; nf < 4; ++nf)
                #pragma unroll
                for (int rr2 = 0; rr2 < 4; ++rr2)
                    lw[(4 * kg + rr2) * 68 + nf * 16 + lrow] = acc[mf][nf][rr2];
            // gather rows as float4: lane covers cols colb..colb+3 of row 4*ri+kg
            #pragma unroll
            for (int ri = 0; ri < 4; ++ri) {
                const int lr2 = 4 * ri + kg;
                float4 v = *reinterpret_cast<const float4*>(&lw[lr2 * 68 + colb]);
                v.x += b4.x; v.y += b4.y; v.z += b4.z; v.w += b4.w;
                const int row = bm + wm * 128 + mf * 16 + lr2;
                *reinterpret_cast<float4*>(&C[(size_t)row * ldc + col]) = v;
            }
        }
    }
#undef STAGE256
}

// ---------------------------------------------------------------------------
// Depthwise causal conv (K=4) + bias + SiLU -> u fp32 + u bf16.
// float4-vectorized (R13 win).
// ---------------------------------------------------------------------------
__global__ __launch_bounds__(256)
void conv_silu_kernel(const float* __restrict__ xz, const float* __restrict__ cw,
                      const float* __restrict__ cb, float* __restrict__ u,
                      unsigned short* __restrict__ u_bf)
{
    int idx = blockIdx.x * 256 + threadIdx.x;       // over T*ED/4
    if (idx >= T_ * ED_ / 4) return;
    const int epb = ED_ / 4;                        // 384
    int t  = idx / epb;
    int e0 = (idx - t * epb) * 4;
    int l  = t % L_;

    const float4 w0 = *reinterpret_cast<const float4*>(&cw[(e0 + 0) * KC_]);
    const float4 w1 = *reinterpret_cast<const float4*>(&cw[(e0 + 1) * KC_]);
    const float4 w2 = *reinterpret_cast<const float4*>(&cw[(e0 + 2) * KC_]);
    const float4 w3 = *reinterpret_cast<const float4*>(&cw[(e0 + 3) * KC_]);
    const float t0a[4] = {w0.x, w0.y, w0.z, w0.w};
    const float t1a[4] = {w1.x, w1.y, w1.z, w1.w};
    const float t2a[4] = {w2.x, w2.y, w2.z, w2.w};
    const float t3a[4] = {w3.x, w3.y, w3.z, w3.w};

    float4 acc = *reinterpret_cast<const float4*>(&cb[e0]);
    #pragma unroll
    for (int k = 0; k < KC_; ++k) {
        int ll = l - (KC_ - 1) + k;
        if (ll >= 0) {
            float4 v = *reinterpret_cast<const float4*>(
                &xz[(size_t)(t - (KC_ - 1) + k) * (2 * ED_) + e0]);
            acc.x = fmaf(t0a[k], v.x, acc.x);
            acc.y = fmaf(t1a[k], v.y, acc.y);
            acc.z = fmaf(t2a[k], v.z, acc.z);
            acc.w = fmaf(t3a[k], v.w, acc.w);
        }
    }
    float4 o;
    o.x = siluf(acc.x); o.y = siluf(acc.y); o.z = siluf(acc.z); o.w = siluf(acc.w);
    *reinterpret_cast<float4*>(&u[(size_t)t * ED_ + e0]) = o;
    ushort4 ob;
    ob.x = f2bf1(o.x); ob.y = f2bf1(o.y); ob.z = f2bf1(o.z); ob.w = f2bf1(o.w);
    *reinterpret_cast<ushort4*>(&u_bf[(size_t)t * ED_ + e0]) = ob;
}

// ---------------------------------------------------------------------------
// Chunked selective scan, e-lane layout (round-11 win: coalesced loads,
// states in registers, no shuffles)
// ---------------------------------------------------------------------------
__global__ __launch_bounds__(256)
void scanA_kernel(const float* __restrict__ delta,
                  const float* __restrict__ dbc,
                  const float* __restrict__ u,
                  const float* __restrict__ A_log,
                  float* __restrict__ hend,
                  float* __restrict__ Pcum)
{
    const int b = blockIdx.z;
    const int c = blockIdx.y;
    const int e = blockIdx.x * 256 + threadIdx.x;

    float Aen[16], h[16], P[16];
    #pragma unroll
    for (int n = 0; n < NS_; ++n) {
        Aen[n] = -__expf(A_log[e * NS_ + n]);
        h[n] = 0.f; P[n] = 1.f;
    }

    const int t0 = b * L_ + c * SCH_;
    #pragma unroll 2
    for (int l = 0; l < SCH_; ++l) {
        const size_t t = (size_t)(t0 + l);
        const float d  = delta[t * ED_ + e];
        const float uu = u[t * ED_ + e];
        const float du = d * uu;
        const float4* Bv = reinterpret_cast<const float4*>(&dbc[t * DBCP_ + DTR_]);
        #pragma unroll
        for (int g = 0; g < 4; ++g) {
            const float4 Bg = Bv[g];
            const float Bx[4] = {Bg.x, Bg.y, Bg.z, Bg.w};
            #pragma unroll
            for (int j = 0; j < 4; ++j) {
                const int n = g * 4 + j;
                const float a = __expf(d * Aen[n]);
                h[n] = fmaf(a, h[n], du * Bx[j]);
                P[n] *= a;
            }
        }
    }
    const size_t base = ((size_t)(b * NCH_ + c) * 16) * ED_ + e;
    #pragma unroll
    for (int n = 0; n < NS_; ++n) {
        hend[base + (size_t)n * ED_] = h[n];
        Pcum[base + (size_t)n * ED_] = P[n];
    }
}

// carry pass: thread = (b, n, e); loops chunks; all loads/stores e-coalesced
__global__ __launch_bounds__(256)
void scanB2_kernel(const float* __restrict__ hend,
                   const float* __restrict__ Pcum,
                   float* __restrict__ carry)
{
    const int i = blockIdx.x * 256 + threadIdx.x;   // over B*16*ED
    const int e = i % ED_;
    const int n = (i / ED_) % 16;
    const int b = i / (16 * ED_);
    float cr = 0.f;
    #pragma unroll 4
    for (int c = 0; c < NCH_; ++c) {
        const size_t idx = (((size_t)(b * NCH_ + c) * 16) + n) * ED_ + e;
        carry[idx] = cr;
        cr = fmaf(Pcum[idx], cr, hend[idx]);
    }
}

__global__ __launch_bounds__(256)
void scanC_kernel(const float* __restrict__ delta,
                  const float* __restrict__ dbc,
                  const float* __restrict__ u,
                  const float* __restrict__ xz,
                  const float* __restrict__ A_log,
                  const float* __restrict__ Dp,
                  const float* __restrict__ carry,
                  unsigned short* __restrict__ y_bf)
{
    const int b = blockIdx.z;
    const int c = blockIdx.y;
    const int e = blockIdx.x * 256 + threadIdx.x;

    const float De = Dp[e];
    float Aen[16], h[16];
    const size_t cbase = ((size_t)(b * NCH_ + c) * 16) * ED_ + e;
    #pragma unroll
    for (int n = 0; n < NS_; ++n) {
        Aen[n] = -__expf(A_log[e * NS_ + n]);
        h[n] = carry[cbase + (size_t)n * ED_];
    }

    const int t0 = b * L_ + c * SCH_;
    #pragma unroll 2
    for (int l = 0; l < SCH_; ++l) {
        const size_t t = (size_t)(t0 + l);
        const float d  = delta[t * ED_ + e];
        const float uu = u[t * ED_ + e];
        const float du = d * uu;
        const float4* Bv = reinterpret_cast<const float4*>(&dbc[t * DBCP_ + DTR_]);
        const float4* Cv = reinterpret_cast<const float4*>(&dbc[t * DBCP_ + DTR_ + NS_]);
        float p = 0.f;
        #pragma unroll
        for (int g = 0; g < 4; ++g) {
            const float4 Bg = Bv[g];
            const float4 Cg = Cv[g];
            const float Bx[4] = {Bg.x, Bg.y, Bg.z, Bg.w};
            const float Cx[4] = {Cg.x, Cg.y, Cg.z, Cg.w};
            #pragma unroll
            for (int j = 0; j < 4; ++j) {
                const int n = g * 4 + j;
                const float a = __expf(d * Aen[n]);
                h[n] = fmaf(a, h[n], du * Bx[j]);
                p = fmaf(h[n], Cx[j], p);
            }
        }
        const float ys = p + uu * De;
        const float rr = xz[t * (2 * ED_) + ED_ + e];
        y_bf[t * ED_ + e] = f2bf1(ys * siluf(rr));
    }
}

// ---------------------------------------------------------------------------
// LayerNorm over DM, in place; also emits bf16
// ---------------------------------------------------------------------------
__global__ __launch_bounds__(256)
void ln_kernel(float* __restrict__ x, const float* __restrict__ g,
               const float* __restrict__ bta, unsigned short* __restrict__ x_bf)
{
    const int t = blockIdx.x;
    float* xr = x + (size_t)t * DM_;
    unsigned short* xb = x_bf + (size_t)t * DM_;
    const int tid = threadIdx.x;

    float v0 = xr[tid], v1 = xr[tid + 256], v2 = xr[tid + 512];
    float s  = v0 + v1 + v2;
    float sq = v0 * v0 + v1 * v1 + v2 * v2;

    __shared__ float s1[256], s2[256];
    s1[tid] = s; s2[tid] = sq;
    __syncthreads();
    for (int off = 128; off > 0; off >>= 1) {
        if (tid < off) { s1[tid] += s1[tid + off]; s2[tid] += s2[tid + off]; }
        __syncthreads();
    }
    const float mu  = s1[0] * (1.f / DM_);
    const float var = s2[0] * (1.f / DM_) - mu * mu;
    const float rs  = rsqrtf(var + 1e-5f);

    float o0 = (v0 - mu) * rs * g[tid]       + bta[tid];
    float o1 = (v1 - mu) * rs * g[tid + 256] + bta[tid + 256];
    float o2 = (v2 - mu) * rs * g[tid + 512] + bta[tid + 512];
    xr[tid] = o0;       xb[tid] = f2bf1(o0);
    xr[tid + 256] = o1; xb[tid + 256] = f2bf1(o1);
    xr[tid + 512] = o2; xb[tid + 512] = f2bf1(o2);
}

// ---------------------------------------------------------------------------
extern "C" void kernel_launch(void* const* d_in, const int* in_sizes, int n_in,
                              void* d_out, int out_size, void* d_ws, size_t ws_size,
                              hipStream_t stream)
{
    const int*   ids       = (const int*)  d_in[0];
    const float* emb       = (const float*)d_in[1];
    const float* in_proj_w = (const float*)d_in[2];
    const float* conv_w    = (const float*)d_in[3];
    const float* conv_b    = (const float*)d_in[4];
    const float* x_proj_w  = (const float*)d_in[5];
    const float* dt_proj_w = (const float*)d_in[6];
    const float* dt_proj_b = (const float*)d_in[7];
    const float* A_log     = (const float*)d_in[8];
    const float* Dp        = (const float*)d_in[9];
    const float* out_proj_w= (const float*)d_in[10];
    const float* ln_g      = (const float*)d_in[11];
    const float* ln_b      = (const float*)d_in[12];
    const float* head_w    = (const float*)d_in[13];
    const float* head_b    = (const float*)d_in[14];
    float* out = (float*)d_out;

    // fp32 workspace
    float* ws    = (float*)d_ws;
    float* x     = ws;                              // T*DM
    float* xz    = x     + (size_t)T_ * DM_;        // T*2ED
    float* u     = xz    + (size_t)T_ * 2 * ED_;    // T*ED
    float* dbc   = u     + (size_t)T_ * ED_;        // T*128 (padded)
    float* delta = dbc   + (size_t)T_ * DBCP_;      // T*ED
    float* hend  = delta + (size_t)T_ * ED_;        // B*NCH*16*ED
    float* Pcum  = hend  + (size_t)B_ * NCH_ * 16 * ED_;
    float* carry = Pcum  + (size_t)B_ * NCH_ * 16 * ED_;
    float* part  = carry + (size_t)B_ * NCH_ * 16 * ED_;  // 4*T*DM floats
    // bf16 workspace
    unsigned short* bf = (unsigned short*)(part + (size_t)4 * T_ * DM_);
    unsigned short* x_bf    = bf;                                 // T*DM
    unsigned short* u_bf    = x_bf    + (size_t)T_ * DM_;         // T*ED
    unsigned short* y_bf    = u_bf    + (size_t)T_ * ED_;         // T*ED
    unsigned short* dbc_bf  = y_bf    + (size_t)T_ * ED_;         // T*128
    unsigned short* inw_bf  = dbc_bf  + (size_t)T_ * DBCP_;       // NL*2ED*DM
    unsigned short* outw_bf = inw_bf  + (size_t)NL_ * 2 * ED_ * DM_;  // NL*DM*ED
    unsigned short* wx_bf   = outw_bf + (size_t)NL_ * DM_ * ED_;      // NL*128*ED
    unsigned short* wdt_bf  = wx_bf   + (size_t)NL_ * 128 * ED_;      // NL*ED*64
    unsigned short* hw_bf   = wdt_bf  + (size_t)NL_ * ED_ * 64;       // V*DM

    // ---- upfront: embedding + ALL weight conversions in one dispatch
    embed_kernel<<<(T_ * DM_ + 255) / 256, 256, 0, stream>>>(ids, emb, x_bf);
    prep_kernel<<<PREP_NB, 256, 0, stream>>>(
        in_proj_w, inw_bf, out_proj_w, outw_bf, x_proj_w, wx_bf,
        dt_proj_w, wdt_bf, head_w, hw_bf);

    for (int i = 0; i < NL_; ++i) {
        const unsigned short* w_in  = inw_bf  + (size_t)i * 2 * ED_ * DM_;
        const float*          cw    = conv_w  + (size_t)i * ED_ * KC_;
        const float*          cb    = conv_b  + (size_t)i * ED_;
        const unsigned short* w_x   = wx_bf   + (size_t)i * 128 * ED_;
        const unsigned short* w_dt  = wdt_bf  + (size_t)i * ED_ * 64;
        const float*          b_dt  = dt_proj_b + (size_t)i * ED_;
        const float*          al    = A_log   + (size_t)i * ED_ * NS_;
        const float*          dpar  = Dp      + (size_t)i * ED_;
        const unsigned short* w_out = outw_bf + (size_t)i * DM_ * ED_;

        // xz = x @ w_in^T  (4096 x 3072, K=768) — 256² deep-pipelined structure
        gemm256_bf16<<<(T_/256) * (2*ED_/256), 512, 0, stream>>>(
            x_bf, DM_, w_in, DM_, xz, 2 * ED_, nullptr, T_/256, DM_);

        // u = silu(depthwise causal conv + cb)  (+ bf16), float4 vectorized
        conv_silu_kernel<<<(T_ * ED_ / 4 + 255) / 256, 256, 0, stream>>>(
            xz, cw, cb, u, u_bf);

        // dbc = u @ w_x_pad^T  (4096 x 128, K=1536) — split-K S=8 (32->256 blocks)
        gemm_splitk_bf16<<<(T_/128) * 1 * 8, 256, 0, stream>>>(
            u_bf, ED_, w_x, ED_, part, DBCP_, T_/128, 8, ED_/8);
        reduce_splitk<<<(T_ * DBCP_ / 4 + 255) / 256, 256, 0, stream>>>(
            part, dbc, dbc_bf, T_ * DBCP_ / 4, 8);

        // delta = softplus(dbc[:, :64] @ w_dt_pad^T + b_dt)  (4096 x 1536, K=64)
        gemm_bf16<1, false><<<(T_/128) * (ED_/128), 256, 0, stream>>>(
            dbc_bf, DBCP_, w_dt, 64, delta, nullptr, ED_, b_dt, T_/128, 64);

        // chunked selective scan + gating -> y_bf (e-lane layout, 3 passes)
        scanA_kernel<<<dim3(ED_ / 256, NCH_, B_), 256, 0, stream>>>(
            delta, dbc, u, al, hend, Pcum);
        scanB2_kernel<<<(B_ * 16 * ED_) / 256, 256, 0, stream>>>(hend, Pcum, carry);
        scanC_kernel<<<dim3(ED_ / 256, NCH_, B_), 256, 0, stream>>>(
            delta, dbc, u, xz, al, dpar, carry, y_bf);

        // x = y @ w_out^T  (4096 x 768, K=1536) — split-K S=4 (192->768 blocks)
        gemm_splitk_bf16<<<(T_/128) * (DM_/128) * 4, 256, 0, stream>>>(
            y_bf, ED_, w_out, ED_, part, DM_, T_/128, 4, ED_/4);
        reduce_splitk<<<(T_ * DM_ / 4 + 255) / 256, 256, 0, stream>>>(
            part, x, x_bf, T_ * DM_ / 4, 4);
    }

    // LayerNorm (fp32 in place + bf16), then head with the 256² deep-pipelined GEMM
    ln_kernel<<<T_, 256, 0, stream>>>(x, ln_g, ln_b, x_bf);
    gemm256_bf16<<<(T_/256) * (V_/256), 512, 0, stream>>>(
        x_bf, DM_, hw_bf, DM_, out, V_, head_b, T_/256, DM_);
}